// Round 1
// baseline (1644.701 us; speedup 1.0000x reference)
//
#include <hip/hip_runtime.h>
#include <hip/hip_bf16.h>
#include <math.h>

// ---------------------------------------------------------------------------
// MolGAT: 3x GATv2 (heads=1, D=64) + MLP(64->128->64->1, BN train-stats) +
// global mean pool over G=256 graphs.
// Strategy: build CSR grouped by dst once per call; per-node online-softmax
// aggregation (one wave per node, lane = channel). fp32 everywhere.
// ---------------------------------------------------------------------------

#define WAVE 64

// ---------------- CSR build ----------------

__global__ void k_hist(const int* __restrict__ dst, int* __restrict__ deg,
                       int nE, int n) {
    int i = blockIdx.x * blockDim.x + threadIdx.x;
    int tot = nE + n;
    if (i < tot) {
        int d = (i < nE) ? dst[i] : (i - nE);   // self loops appended
        atomicAdd(&deg[d], 1);
    }
}

__global__ __launch_bounds__(1024) void k_scan1(const int* __restrict__ deg,
                                                int* __restrict__ rowptr,
                                                int* __restrict__ bsum, int n) {
    __shared__ int buf[1024];
    int i = blockIdx.x * 1024 + threadIdx.x;
    int v = (i < n) ? deg[i] : 0;
    buf[threadIdx.x] = v;
    __syncthreads();
    for (int off = 1; off < 1024; off <<= 1) {
        int t = (threadIdx.x >= off) ? buf[threadIdx.x - off] : 0;
        __syncthreads();
        buf[threadIdx.x] += t;
        __syncthreads();
    }
    if (i < n) rowptr[i] = buf[threadIdx.x] - v;   // block-local exclusive
    if (threadIdx.x == 1023) bsum[blockIdx.x] = buf[1023];
}

__global__ void k_scan2(int* __restrict__ bsum, int nb,
                        int* __restrict__ rowptr, int n) {
    // single thread: exclusive scan of block sums (nb ~ 98)
    int run = 0;
    for (int i = 0; i < nb; ++i) { int v = bsum[i]; bsum[i] = run; run += v; }
    rowptr[n] = run;
}

__global__ __launch_bounds__(1024) void k_scan3(int* __restrict__ rowptr,
                                                const int* __restrict__ bsum,
                                                int n) {
    int i = blockIdx.x * 1024 + threadIdx.x;
    if (i < n) rowptr[i] += bsum[blockIdx.x];
}

__global__ void k_fill(const int* __restrict__ srcA, const int* __restrict__ dstA,
                       int* __restrict__ cursor, int* __restrict__ csr_src,
                       int nE, int n) {
    int i = blockIdx.x * blockDim.x + threadIdx.x;
    int tot = nE + n;
    if (i < tot) {
        int s, d;
        if (i < nE) { s = srcA[i]; d = dstA[i]; }
        else        { s = d = i - nE; }
        int pos = atomicAdd(&cursor[d], 1);
        csr_src[pos] = s;
    }
}

// ---------------- GAT linear: xl = h@Wl+bl, xr = h@Wr+br ----------------

__global__ __launch_bounds__(256) void k_gat_gemm(
        const float* __restrict__ hin,
        const float* __restrict__ Wl, const float* __restrict__ bl,
        const float* __restrict__ Wr, const float* __restrict__ br,
        float* __restrict__ xl, float* __restrict__ xr, int n) {
    __shared__ float sWl[64 * 64];
    __shared__ float sWr[64 * 64];
    __shared__ float rows[4][64];
    int tid = threadIdx.x;
    for (int i = tid; i < 4096; i += 256) { sWl[i] = Wl[i]; sWr[i] = Wr[i]; }
    __syncthreads();
    int col = tid & 63, rl = tid >> 6;
    float blc = bl[col], brc = br[col];
    for (int r0 = blockIdx.x * 4; r0 < n; r0 += gridDim.x * 4) {
        int r = r0 + rl;
        // each wave stages its own row (wave-coherent LDS use, no barrier)
        rows[rl][col] = (r < n) ? hin[r * 64 + col] : 0.f;
        float al = blc, ar = brc;
        #pragma unroll
        for (int k = 0; k < 64; ++k) {
            float h = rows[rl][k];
            al = fmaf(h, sWl[k * 64 + col], al);
            ar = fmaf(h, sWr[k * 64 + col], ar);
        }
        if (r < n) { xl[r * 64 + col] = al; xr[r * 64 + col] = ar; }
    }
}

// ---------------- GAT edge aggregation (online softmax per dst) ----------------

__global__ __launch_bounds__(256) void k_gat_edge(
        const float* __restrict__ xl, const float* __restrict__ xr,
        const int* __restrict__ rowptr, const int* __restrict__ csr_src,
        const float* __restrict__ att, const float* __restrict__ bias,
        float* __restrict__ hout, int n, int do_relu) {
    int node = blockIdx.x * 4 + (threadIdx.x >> 6);
    if (node >= n) return;
    int lane = threadIdx.x & 63;
    float att_c = att[lane];
    float xr_c  = xr[node * 64 + lane];
    int beg = rowptr[node], end = rowptr[node + 1];
    float m = -INFINITY, s = 0.f, acc = 0.f;
    for (int k = beg; k < end; ++k) {
        int src = csr_src[k];
        float v = xl[src * 64 + lane];
        float t = v + xr_c;
        t = (t > 0.f) ? t : 0.2f * t;          // leaky relu, slope 0.2
        float p = t * att_c;
        #pragma unroll
        for (int off = 32; off; off >>= 1) p += __shfl_xor(p, off);
        float mn = fmaxf(m, p);
        float sc = __expf(m - mn);             // first iter: exp(-inf)=0
        float w  = __expf(p - mn);
        s   = s * sc + w;
        acc = acc * sc + w * v;
        m = mn;
    }
    float o = acc / s + bias[lane];
    if (do_relu) o = fmaxf(o, 0.f);
    hout[node * 64 + lane] = o;
}

// ---------------- MLP GEMM (+ optional BN stats accumulation) ----------------

template <int DIN, int DOUT>
__global__ __launch_bounds__(256) void k_mlp_gemm(
        const float* __restrict__ hin, const float* __restrict__ W,
        const float* __restrict__ bias, float* __restrict__ z,
        float* __restrict__ stat_sum, float* __restrict__ stat_sq,
        int n, int do_stats) {
    constexpr int RP = 256 / DOUT;   // rows per iteration
    __shared__ float sW[DIN * DOUT];
    __shared__ float rows[RP][DIN];
    __shared__ float red[256];
    int tid = threadIdx.x;
    for (int i = tid; i < DIN * DOUT; i += 256) sW[i] = W[i];
    __syncthreads();
    int col = tid % DOUT, rl = tid / DOUT;
    float bc = bias[col];
    float lsum = 0.f, lsq = 0.f;
    for (int r0 = blockIdx.x * RP; r0 < n; r0 += gridDim.x * RP) {
        // cooperative row staging
        for (int i = tid; i < RP * DIN; i += 256) {
            int rr = r0 + i / DIN;
            rows[i / DIN][i % DIN] = (rr < n) ? hin[rr * DIN + (i % DIN)] : 0.f;
        }
        __syncthreads();
        int r = r0 + rl;
        float a = bc;
        #pragma unroll
        for (int k = 0; k < DIN; ++k) a = fmaf(rows[rl][k], sW[k * DOUT + col], a);
        if (r < n) {
            z[r * DOUT + col] = a;
            lsum += a;
            lsq  = fmaf(a, a, lsq);
        }
        __syncthreads();
    }
    if (do_stats) {
        red[tid] = lsum; __syncthreads();
        if (rl == 0) {
            float t = 0.f;
            for (int j = 0; j < RP; ++j) t += red[j * DOUT + col];
            atomicAdd(&stat_sum[col], t);
        }
        __syncthreads();
        red[tid] = lsq; __syncthreads();
        if (rl == 0) {
            float t = 0.f;
            for (int j = 0; j < RP; ++j) t += red[j * DOUT + col];
            atomicAdd(&stat_sq[col], t);
        }
    }
}

__global__ void k_bn_fin(const float* __restrict__ ssum, const float* __restrict__ ssq,
                         float* __restrict__ mu, float* __restrict__ inv,
                         int n, int dout) {
    int c = threadIdx.x;
    if (c >= dout) return;
    float m = ssum[c] / (float)n;
    float v = ssq[c] / (float)n - m * m;
    mu[c]  = m;
    inv[c] = rsqrtf(fmaxf(v, 0.f) + 1e-5f);
}

__global__ void k_bn_apply(float* __restrict__ z, const float* __restrict__ mu,
                           const float* __restrict__ inv, const float* __restrict__ g,
                           const float* __restrict__ be, long total4, int dout) {
    long i = (long)blockIdx.x * blockDim.x + threadIdx.x;
    if (i >= total4) return;
    float4 v = reinterpret_cast<float4*>(z)[i];
    int c = (int)((i * 4) % dout);
    v.x = fmaxf(fmaf((v.x - mu[c]) * inv[c], g[c], be[c]), 0.f);
    v.y = fmaxf(fmaf((v.y - mu[c + 1]) * inv[c + 1], g[c + 1], be[c + 1]), 0.f);
    v.z = fmaxf(fmaf((v.z - mu[c + 2]) * inv[c + 2], g[c + 2], be[c + 2]), 0.f);
    v.w = fmaxf(fmaf((v.w - mu[c + 3]) * inv[c + 3], g[c + 3], be[c + 3]), 0.f);
    reinterpret_cast<float4*>(z)[i] = v;
}

// ---------------- final linear (64->1) + mean-pool ----------------

__global__ __launch_bounds__(256) void k_final_pool(
        const float* __restrict__ h2, const float* __restrict__ w2,
        const float* __restrict__ b2, const int* __restrict__ batch,
        float* __restrict__ sums, int* __restrict__ cnts, int n) {
    int node = blockIdx.x * 4 + (threadIdx.x >> 6);
    if (node >= n) return;
    int lane = threadIdx.x & 63;
    float p = h2[node * 64 + lane] * w2[lane];
    #pragma unroll
    for (int off = 32; off; off >>= 1) p += __shfl_xor(p, off);
    if (lane == 0) {
        int g = batch[node];
        atomicAdd(&sums[g], p + b2[0]);
        atomicAdd(&cnts[g], 1);
    }
}

__global__ void k_out(const float* __restrict__ sums, const int* __restrict__ cnts,
                      float* __restrict__ out, int g) {
    int i = blockIdx.x * blockDim.x + threadIdx.x;
    if (i < g) out[i] = sums[i] / fmaxf((float)cnts[i], 1.f);
}

// ---------------------------------------------------------------------------

extern "C" void kernel_launch(void* const* d_in, const int* in_sizes, int n_in,
                              void* d_out, int out_size, void* d_ws, size_t ws_size,
                              hipStream_t stream) {
    const float* x     = (const float*)d_in[0];
    const int*   ei    = (const int*)d_in[1];
    const int*   batch = (const int*)d_in[2];

    const int N = in_sizes[0] / 64;
    const int E = in_sizes[1] / 2;
    const int G = out_size;
    const int Etot = E + N;

    const int* srcA = ei;
    const int* dstA = ei + E;

    // GAT layer params: d_in[3 + 6l ..]
    const float* Wl[3]; const float* bl[3]; const float* Wr[3];
    const float* br[3]; const float* att[3]; const float* bb[3];
    for (int l = 0; l < 3; ++l) {
        int base = 3 + 6 * l;
        Wl[l]  = (const float*)d_in[base + 0];
        bl[l]  = (const float*)d_in[base + 1];
        Wr[l]  = (const float*)d_in[base + 2];
        br[l]  = (const float*)d_in[base + 3];
        att[l] = (const float*)d_in[base + 4];
        bb[l]  = (const float*)d_in[base + 5];
    }
    const float* mW0 = (const float*)d_in[21];
    const float* mb0 = (const float*)d_in[22];
    const float* g0  = (const float*)d_in[23];
    const float* be0 = (const float*)d_in[24];
    const float* mW1 = (const float*)d_in[25];
    const float* mb1 = (const float*)d_in[26];
    const float* g1  = (const float*)d_in[27];
    const float* be1 = (const float*)d_in[28];
    const float* mW2 = (const float*)d_in[29];
    const float* mb2 = (const float*)d_in[30];

    // ---- workspace carve ----
    char* w = (char*)d_ws;
    auto alloc = [&](size_t bytes) -> void* {
        void* p = (void*)w;
        w += (bytes + 255) & ~(size_t)255;
        return p;
    };
    int nb = (N + 1023) / 1024;
    int*   rowptr = (int*)alloc((size_t)(N + 1) * 4);
    int*   cursor = (int*)alloc((size_t)N * 4);        // deg, then fill cursor
    int*   bsum   = (int*)alloc((size_t)(nb + 1) * 4);
    int*   csr    = (int*)alloc((size_t)Etot * 4);
    float* xl     = (float*)alloc((size_t)N * 64 * 4); // xl+xr contiguous -> z
    float* xr     = (float*)alloc((size_t)N * 64 * 4);
    float* h      = (float*)alloc((size_t)N * 64 * 4);
    float* stats  = (float*)alloc(8 * 128 * 4);        // sum/sq/mu/inv x2 layers
    float* pools  = (float*)alloc((size_t)G * 4);
    int*   pcnt   = (int*)alloc((size_t)G * 4);
    float* z      = xl;                                // [N,128] spans xl+xr

    float* sum0 = stats;        float* sq0 = stats + 128;
    float* mu0  = stats + 256;  float* iv0 = stats + 384;
    float* sum1 = stats + 512;  float* sq1 = stats + 640;
    float* mu1  = stats + 768;  float* iv1 = stats + 896;

    // ---- CSR build ----
    hipMemsetAsync(cursor, 0, (size_t)N * 4, stream);
    int ethreads = (Etot + 255) / 256;
    k_hist<<<ethreads, 256, 0, stream>>>(dstA, cursor, E, N);
    k_scan1<<<nb, 1024, 0, stream>>>(cursor, rowptr, bsum, N);
    k_scan2<<<1, 1, 0, stream>>>(bsum, nb, rowptr, N);
    k_scan3<<<nb, 1024, 0, stream>>>(rowptr, bsum, N);
    hipMemcpyAsync(cursor, rowptr, (size_t)N * 4, hipMemcpyDeviceToDevice, stream);
    k_fill<<<ethreads, 256, 0, stream>>>(srcA, dstA, cursor, csr, E, N);

    // ---- 3x GATv2 ----
    int nodeBlocks = (N + 3) / 4;
    const float* hin = x;
    for (int l = 0; l < 3; ++l) {
        k_gat_gemm<<<2048, 256, 0, stream>>>(hin, Wl[l], bl[l], Wr[l], br[l],
                                             xl, xr, N);
        k_gat_edge<<<nodeBlocks, 256, 0, stream>>>(xl, xr, rowptr, csr,
                                                   att[l], bb[l], h, N,
                                                   (l < 2) ? 1 : 0);
        hin = h;
    }

    // ---- MLP layer 0: 64 -> 128, BN, ReLU ----
    hipMemsetAsync(sum0, 0, 2 * 128 * 4, stream);
    k_mlp_gemm<64, 128><<<2048, 256, 0, stream>>>(h, mW0, mb0, z, sum0, sq0, N, 1);
    k_bn_fin<<<1, 128, 0, stream>>>(sum0, sq0, mu0, iv0, N, 128);
    {
        long total4 = (long)N * 128 / 4;
        int blocks = (int)((total4 + 255) / 256);
        k_bn_apply<<<blocks, 256, 0, stream>>>(z, mu0, iv0, g0, be0, total4, 128);
    }

    // ---- MLP layer 1: 128 -> 64, BN, ReLU (writes over h) ----
    hipMemsetAsync(sum1, 0, 2 * 128 * 4, stream);
    k_mlp_gemm<128, 64><<<2048, 256, 0, stream>>>(z, mW1, mb1, h, sum1, sq1, N, 1);
    k_bn_fin<<<1, 64, 0, stream>>>(sum1, sq1, mu1, iv1, N, 64);
    {
        long total4 = (long)N * 64 / 4;
        int blocks = (int)((total4 + 255) / 256);
        k_bn_apply<<<blocks, 256, 0, stream>>>(h, mu1, iv1, g1, be1, total4, 64);
    }

    // ---- final linear + mean pool ----
    hipMemsetAsync(pools, 0, (size_t)G * 4, stream);
    hipMemsetAsync(pcnt, 0, (size_t)G * 4, stream);
    k_final_pool<<<nodeBlocks, 256, 0, stream>>>(h, mW2, mb2, batch, pools, pcnt, N);
    k_out<<<1, 256, 0, stream>>>(pools, pcnt, (float*)d_out, G);
}

// Round 2
// 968.303 us; speedup vs baseline: 1.6985x; 1.6985x over previous
//
#include <hip/hip_runtime.h>
#include <hip/hip_bf16.h>
#include <math.h>

// ---------------------------------------------------------------------------
// MolGAT: 3x GATv2 (heads=1, D=64) + MLP(64->128->64->1, BN train-stats) +
// global mean pool over G=256 graphs.
// R1: (a) segmented mean-pool (binary search on sorted batch, no atomics) —
//     old atomic version serialized 100k adds into 256 addresses (349us).
//     (b) 4-way edge unroll in k_gat_edge for load/shuffle ILP.
// ---------------------------------------------------------------------------

#define WAVE 64

// ---------------- CSR build ----------------

__global__ void k_hist(const int* __restrict__ dst, int* __restrict__ deg,
                       int nE, int n) {
    int i = blockIdx.x * blockDim.x + threadIdx.x;
    int tot = nE + n;
    if (i < tot) {
        int d = (i < nE) ? dst[i] : (i - nE);   // self loops appended
        atomicAdd(&deg[d], 1);
    }
}

__global__ __launch_bounds__(1024) void k_scan1(const int* __restrict__ deg,
                                                int* __restrict__ rowptr,
                                                int* __restrict__ bsum, int n) {
    __shared__ int buf[1024];
    int i = blockIdx.x * 1024 + threadIdx.x;
    int v = (i < n) ? deg[i] : 0;
    buf[threadIdx.x] = v;
    __syncthreads();
    for (int off = 1; off < 1024; off <<= 1) {
        int t = (threadIdx.x >= off) ? buf[threadIdx.x - off] : 0;
        __syncthreads();
        buf[threadIdx.x] += t;
        __syncthreads();
    }
    if (i < n) rowptr[i] = buf[threadIdx.x] - v;   // block-local exclusive
    if (threadIdx.x == 1023) bsum[blockIdx.x] = buf[1023];
}

__global__ void k_scan2(int* __restrict__ bsum, int nb,
                        int* __restrict__ rowptr, int n) {
    int run = 0;
    for (int i = 0; i < nb; ++i) { int v = bsum[i]; bsum[i] = run; run += v; }
    rowptr[n] = run;
}

__global__ __launch_bounds__(1024) void k_scan3(int* __restrict__ rowptr,
                                                const int* __restrict__ bsum,
                                                int n) {
    int i = blockIdx.x * 1024 + threadIdx.x;
    if (i < n) rowptr[i] += bsum[blockIdx.x];
}

__global__ void k_fill(const int* __restrict__ srcA, const int* __restrict__ dstA,
                       int* __restrict__ cursor, int* __restrict__ csr_src,
                       int nE, int n) {
    int i = blockIdx.x * blockDim.x + threadIdx.x;
    int tot = nE + n;
    if (i < tot) {
        int s, d;
        if (i < nE) { s = srcA[i]; d = dstA[i]; }
        else        { s = d = i - nE; }
        int pos = atomicAdd(&cursor[d], 1);
        csr_src[pos] = s;
    }
}

// ---------------- GAT linear: xl = h@Wl+bl, xr = h@Wr+br ----------------

__global__ __launch_bounds__(256) void k_gat_gemm(
        const float* __restrict__ hin,
        const float* __restrict__ Wl, const float* __restrict__ bl,
        const float* __restrict__ Wr, const float* __restrict__ br,
        float* __restrict__ xl, float* __restrict__ xr, int n) {
    __shared__ float sWl[64 * 64];
    __shared__ float sWr[64 * 64];
    __shared__ float rows[4][64];
    int tid = threadIdx.x;
    for (int i = tid; i < 4096; i += 256) { sWl[i] = Wl[i]; sWr[i] = Wr[i]; }
    __syncthreads();
    int col = tid & 63, rl = tid >> 6;
    float blc = bl[col], brc = br[col];
    for (int r0 = blockIdx.x * 4; r0 < n; r0 += gridDim.x * 4) {
        int r = r0 + rl;
        rows[rl][col] = (r < n) ? hin[r * 64 + col] : 0.f;
        float al = blc, ar = brc;
        #pragma unroll
        for (int k = 0; k < 64; ++k) {
            float h = rows[rl][k];
            al = fmaf(h, sWl[k * 64 + col], al);
            ar = fmaf(h, sWr[k * 64 + col], ar);
        }
        if (r < n) { xl[r * 64 + col] = al; xr[r * 64 + col] = ar; }
    }
}

// ---------------- GAT edge aggregation (online softmax per dst) ----------------

__global__ __launch_bounds__(256) void k_gat_edge(
        const float* __restrict__ xl, const float* __restrict__ xr,
        const int* __restrict__ rowptr, const int* __restrict__ csr_src,
        const float* __restrict__ att, const float* __restrict__ bias,
        float* __restrict__ hout, int n, int do_relu) {
    int node = blockIdx.x * 4 + (threadIdx.x >> 6);
    if (node >= n) return;
    int lane = threadIdx.x & 63;
    float att_c = att[lane];
    float xr_c  = xr[node * 64 + lane];
    int beg = rowptr[node], end = rowptr[node + 1];
    float m = -INFINITY, s = 0.f, acc = 0.f;
    int k = beg;
    // 4-way unroll: independent gathers + parallel shuffle reduces
    for (; k + 4 <= end; k += 4) {
        int s0 = csr_src[k], s1 = csr_src[k + 1];
        int s2 = csr_src[k + 2], s3 = csr_src[k + 3];
        float v0 = xl[(size_t)s0 * 64 + lane];
        float v1 = xl[(size_t)s1 * 64 + lane];
        float v2 = xl[(size_t)s2 * 64 + lane];
        float v3 = xl[(size_t)s3 * 64 + lane];
        float t0 = v0 + xr_c; t0 = (t0 > 0.f) ? t0 : 0.2f * t0;
        float t1 = v1 + xr_c; t1 = (t1 > 0.f) ? t1 : 0.2f * t1;
        float t2 = v2 + xr_c; t2 = (t2 > 0.f) ? t2 : 0.2f * t2;
        float t3 = v3 + xr_c; t3 = (t3 > 0.f) ? t3 : 0.2f * t3;
        float p0 = t0 * att_c, p1 = t1 * att_c;
        float p2 = t2 * att_c, p3 = t3 * att_c;
        #pragma unroll
        for (int off = 32; off; off >>= 1) {
            p0 += __shfl_xor(p0, off);
            p1 += __shfl_xor(p1, off);
            p2 += __shfl_xor(p2, off);
            p3 += __shfl_xor(p3, off);
        }
        float mx = fmaxf(fmaxf(fmaxf(p0, p1), fmaxf(p2, p3)), m);
        float sc = __expf(m - mx);
        float w0 = __expf(p0 - mx), w1 = __expf(p1 - mx);
        float w2 = __expf(p2 - mx), w3 = __expf(p3 - mx);
        s   = s * sc + ((w0 + w1) + (w2 + w3));
        acc = acc * sc + fmaf(w0, v0, fmaf(w1, v1, fmaf(w2, v2, w3 * v3)));
        m = mx;
    }
    for (; k < end; ++k) {
        int src = csr_src[k];
        float v = xl[(size_t)src * 64 + lane];
        float t = v + xr_c;
        t = (t > 0.f) ? t : 0.2f * t;
        float p = t * att_c;
        #pragma unroll
        for (int off = 32; off; off >>= 1) p += __shfl_xor(p, off);
        float mn = fmaxf(m, p);
        float sc = __expf(m - mn);
        float w  = __expf(p - mn);
        s   = s * sc + w;
        acc = acc * sc + w * v;
        m = mn;
    }
    float o = acc / s + bias[lane];
    if (do_relu) o = fmaxf(o, 0.f);
    hout[node * 64 + lane] = o;
}

// ---------------- MLP GEMM (+ optional BN stats accumulation) ----------------

template <int DIN, int DOUT>
__global__ __launch_bounds__(256) void k_mlp_gemm(
        const float* __restrict__ hin, const float* __restrict__ W,
        const float* __restrict__ bias, float* __restrict__ z,
        float* __restrict__ stat_sum, float* __restrict__ stat_sq,
        int n, int do_stats) {
    constexpr int RP = 256 / DOUT;   // rows per iteration
    __shared__ float sW[DIN * DOUT];
    __shared__ float rows[RP][DIN];
    __shared__ float red[256];
    int tid = threadIdx.x;
    for (int i = tid; i < DIN * DOUT; i += 256) sW[i] = W[i];
    __syncthreads();
    int col = tid % DOUT, rl = tid / DOUT;
    float bc = bias[col];
    float lsum = 0.f, lsq = 0.f;
    for (int r0 = blockIdx.x * RP; r0 < n; r0 += gridDim.x * RP) {
        for (int i = tid; i < RP * DIN; i += 256) {
            int rr = r0 + i / DIN;
            rows[i / DIN][i % DIN] = (rr < n) ? hin[rr * DIN + (i % DIN)] : 0.f;
        }
        __syncthreads();
        int r = r0 + rl;
        float a = bc;
        #pragma unroll
        for (int k = 0; k < DIN; ++k) a = fmaf(rows[rl][k], sW[k * DOUT + col], a);
        if (r < n) {
            z[r * DOUT + col] = a;
            lsum += a;
            lsq  = fmaf(a, a, lsq);
        }
        __syncthreads();
    }
    if (do_stats) {
        red[tid] = lsum; __syncthreads();
        if (rl == 0) {
            float t = 0.f;
            for (int j = 0; j < RP; ++j) t += red[j * DOUT + col];
            atomicAdd(&stat_sum[col], t);
        }
        __syncthreads();
        red[tid] = lsq; __syncthreads();
        if (rl == 0) {
            float t = 0.f;
            for (int j = 0; j < RP; ++j) t += red[j * DOUT + col];
            atomicAdd(&stat_sq[col], t);
        }
    }
}

__global__ void k_bn_fin(const float* __restrict__ ssum, const float* __restrict__ ssq,
                         float* __restrict__ mu, float* __restrict__ inv,
                         int n, int dout) {
    int c = threadIdx.x;
    if (c >= dout) return;
    float m = ssum[c] / (float)n;
    float v = ssq[c] / (float)n - m * m;
    mu[c]  = m;
    inv[c] = rsqrtf(fmaxf(v, 0.f) + 1e-5f);
}

__global__ void k_bn_apply(float* __restrict__ z, const float* __restrict__ mu,
                           const float* __restrict__ inv, const float* __restrict__ g,
                           const float* __restrict__ be, long total4, int dout) {
    long i = (long)blockIdx.x * blockDim.x + threadIdx.x;
    if (i >= total4) return;
    float4 v = reinterpret_cast<float4*>(z)[i];
    int c = (int)((i * 4) % dout);
    v.x = fmaxf(fmaf((v.x - mu[c]) * inv[c], g[c], be[c]), 0.f);
    v.y = fmaxf(fmaf((v.y - mu[c + 1]) * inv[c + 1], g[c + 1], be[c + 1]), 0.f);
    v.z = fmaxf(fmaf((v.z - mu[c + 2]) * inv[c + 2], g[c + 2], be[c + 2]), 0.f);
    v.w = fmaxf(fmaf((v.w - mu[c + 3]) * inv[c + 3], g[c + 3], be[c + 3]), 0.f);
    reinterpret_cast<float4*>(z)[i] = v;
}

// ---------------- final linear (64->1) + segmented mean-pool ----------------
// batch is sorted: block g binary-searches its node range, flat coalesced
// weighted reduction — no atomics.

__global__ __launch_bounds__(256) void k_pool_seg(
        const float* __restrict__ h2, const float* __restrict__ w2,
        const float* __restrict__ b2, const int* __restrict__ batch,
        float* __restrict__ out, int n) {
    int g = blockIdx.x;
    int tid = threadIdx.x;
    // lower_bound(batch, g)
    int lo = 0, hi = n;
    while (lo < hi) { int mid = (lo + hi) >> 1; if (batch[mid] < g) lo = mid + 1; else hi = mid; }
    int start = lo;
    hi = n;
    while (lo < hi) { int mid = (lo + hi) >> 1; if (batch[mid] < g + 1) lo = mid + 1; else hi = mid; }
    int end = lo;
    int cnt = end - start;

    // weighted sum over h2[start:end][:] * w2[col]; stride 256 float4 = 16 rows
    // so each thread's column offset is fixed -> hoist weights to registers.
    int c = (tid << 2) & 63;
    float wa = w2[c], wb = w2[c + 1], wc = w2[c + 2], wd = w2[c + 3];
    const float4* b4 = reinterpret_cast<const float4*>(h2 + (size_t)start * 64);
    long total4 = (long)cnt * 16;   // cnt*64/4
    float acc = 0.f;
    for (long i = tid; i < total4; i += 256) {
        float4 v = b4[i];
        acc = fmaf(v.x, wa, acc);
        acc = fmaf(v.y, wb, acc);
        acc = fmaf(v.z, wc, acc);
        acc = fmaf(v.w, wd, acc);
    }
    __shared__ float red[256];
    red[tid] = acc; __syncthreads();
    for (int off = 128; off; off >>= 1) {
        if (tid < off) red[tid] += red[tid + off];
        __syncthreads();
    }
    if (tid == 0) out[g] = (cnt > 0) ? red[0] / (float)cnt + b2[0] : 0.f;
}

// ---------------------------------------------------------------------------

extern "C" void kernel_launch(void* const* d_in, const int* in_sizes, int n_in,
                              void* d_out, int out_size, void* d_ws, size_t ws_size,
                              hipStream_t stream) {
    const float* x     = (const float*)d_in[0];
    const int*   ei    = (const int*)d_in[1];
    const int*   batch = (const int*)d_in[2];

    const int N = in_sizes[0] / 64;
    const int E = in_sizes[1] / 2;
    const int G = out_size;
    const int Etot = E + N;

    const int* srcA = ei;
    const int* dstA = ei + E;

    const float* Wl[3]; const float* bl[3]; const float* Wr[3];
    const float* br[3]; const float* att[3]; const float* bb[3];
    for (int l = 0; l < 3; ++l) {
        int base = 3 + 6 * l;
        Wl[l]  = (const float*)d_in[base + 0];
        bl[l]  = (const float*)d_in[base + 1];
        Wr[l]  = (const float*)d_in[base + 2];
        br[l]  = (const float*)d_in[base + 3];
        att[l] = (const float*)d_in[base + 4];
        bb[l]  = (const float*)d_in[base + 5];
    }
    const float* mW0 = (const float*)d_in[21];
    const float* mb0 = (const float*)d_in[22];
    const float* g0  = (const float*)d_in[23];
    const float* be0 = (const float*)d_in[24];
    const float* mW1 = (const float*)d_in[25];
    const float* mb1 = (const float*)d_in[26];
    const float* g1  = (const float*)d_in[27];
    const float* be1 = (const float*)d_in[28];
    const float* mW2 = (const float*)d_in[29];
    const float* mb2 = (const float*)d_in[30];

    // ---- workspace carve ----
    char* w = (char*)d_ws;
    auto alloc = [&](size_t bytes) -> void* {
        void* p = (void*)w;
        w += (bytes + 255) & ~(size_t)255;
        return p;
    };
    int nb = (N + 1023) / 1024;
    int*   rowptr = (int*)alloc((size_t)(N + 1) * 4);
    int*   cursor = (int*)alloc((size_t)N * 4);
    int*   bsum   = (int*)alloc((size_t)(nb + 1) * 4);
    int*   csr    = (int*)alloc((size_t)Etot * 4);
    float* xl     = (float*)alloc((size_t)N * 64 * 4); // xl+xr contiguous -> z
    float* xr     = (float*)alloc((size_t)N * 64 * 4);
    float* h      = (float*)alloc((size_t)N * 64 * 4);
    float* stats  = (float*)alloc(8 * 128 * 4);
    float* z      = xl;                                // [N,128] spans xl+xr

    float* sum0 = stats;        float* sq0 = stats + 128;
    float* mu0  = stats + 256;  float* iv0 = stats + 384;
    float* sum1 = stats + 512;  float* sq1 = stats + 640;
    float* mu1  = stats + 768;  float* iv1 = stats + 896;

    // ---- CSR build ----
    hipMemsetAsync(cursor, 0, (size_t)N * 4, stream);
    int ethreads = (Etot + 255) / 256;
    k_hist<<<ethreads, 256, 0, stream>>>(dstA, cursor, E, N);
    k_scan1<<<nb, 1024, 0, stream>>>(cursor, rowptr, bsum, N);
    k_scan2<<<1, 1, 0, stream>>>(bsum, nb, rowptr, N);
    k_scan3<<<nb, 1024, 0, stream>>>(rowptr, bsum, N);
    hipMemcpyAsync(cursor, rowptr, (size_t)N * 4, hipMemcpyDeviceToDevice, stream);
    k_fill<<<ethreads, 256, 0, stream>>>(srcA, dstA, cursor, csr, E, N);

    // ---- 3x GATv2 ----
    int nodeBlocks = (N + 3) / 4;
    const float* hin = x;
    for (int l = 0; l < 3; ++l) {
        k_gat_gemm<<<2048, 256, 0, stream>>>(hin, Wl[l], bl[l], Wr[l], br[l],
                                             xl, xr, N);
        k_gat_edge<<<nodeBlocks, 256, 0, stream>>>(xl, xr, rowptr, csr,
                                                   att[l], bb[l], h, N,
                                                   (l < 2) ? 1 : 0);
        hin = h;
    }

    // ---- MLP layer 0: 64 -> 128, BN, ReLU ----
    hipMemsetAsync(sum0, 0, 2 * 128 * 4, stream);
    k_mlp_gemm<64, 128><<<2048, 256, 0, stream>>>(h, mW0, mb0, z, sum0, sq0, N, 1);
    k_bn_fin<<<1, 128, 0, stream>>>(sum0, sq0, mu0, iv0, N, 128);
    {
        long total4 = (long)N * 128 / 4;
        int blocks = (int)((total4 + 255) / 256);
        k_bn_apply<<<blocks, 256, 0, stream>>>(z, mu0, iv0, g0, be0, total4, 128);
    }

    // ---- MLP layer 1: 128 -> 64, BN, ReLU (writes over h) ----
    hipMemsetAsync(sum1, 0, 2 * 128 * 4, stream);
    k_mlp_gemm<128, 64><<<2048, 256, 0, stream>>>(z, mW1, mb1, h, sum1, sq1, N, 1);
    k_bn_fin<<<1, 64, 0, stream>>>(sum1, sq1, mu1, iv1, N, 64);
    {
        long total4 = (long)N * 64 / 4;
        int blocks = (int)((total4 + 255) / 256);
        k_bn_apply<<<blocks, 256, 0, stream>>>(h, mu1, iv1, g1, be1, total4, 64);
    }

    // ---- final linear + segmented mean pool ----
    k_pool_seg<<<G, 256, 0, stream>>>(h, mW2, mb2, batch, (float*)d_out, N);
}

// Round 3
// 868.099 us; speedup vs baseline: 1.8946x; 1.1154x over previous
//
#include <hip/hip_runtime.h>
#include <hip/hip_bf16.h>
#include <math.h>

// ---------------------------------------------------------------------------
// MolGAT: 3x GATv2 (heads=1, D=64) + MLP(64->128->64->1, BN train-stats) +
// global mean pool over G=256 graphs.
// R2: (a) bucketed two-level CSR build — old k_fill had 16x write
//     amplification (108MB HBM writes for 6.8MB payload) from random 4B
//     scatter across XCDs. New: coarse 512-node buckets, LDS-run partition,
//     per-bucket LDS fine fill (writes stay XCD-local, full lines).
//     (b) 8-wide predicated unroll in k_gat_edge (p=-inf for tail slots).
//     (c) BN-apply+ReLU fused into consumers (mlp_gemm1 staging / pool).
// ---------------------------------------------------------------------------

#define BSHIFT 9
#define BSIZE  512   // nodes per bucket
#define STAGE_CAP 24576

// ---------------- bucketed CSR build ----------------

__global__ __launch_bounds__(256) void k_bcount(const int* __restrict__ dstA,
                                                int* __restrict__ bcnt,
                                                int nE, int n) {
    __shared__ int h[512];
    int t = threadIdx.x;
    h[t] = 0; h[t + 256] = 0;
    __syncthreads();
    int tot = nE + n;
    for (int i = blockIdx.x * 256 + t; i < tot; i += gridDim.x * 256) {
        int d = (i < nE) ? dstA[i] : (i - nE);   // self loops appended
        atomicAdd(&h[d >> BSHIFT], 1);
    }
    __syncthreads();
    if (h[t])       atomicAdd(&bcnt[t], h[t]);
    if (h[t + 256]) atomicAdd(&bcnt[t + 256], h[t + 256]);
}

__global__ __launch_bounds__(512) void k_bscan(const int* __restrict__ bcnt,
                                               int* __restrict__ bbase,
                                               int* __restrict__ bcur,
                                               int* __restrict__ rowptr,
                                               int nb, int n, int etot) {
    __shared__ int buf[512];
    int t = threadIdx.x;
    int v = (t < nb) ? bcnt[t] : 0;
    buf[t] = v;
    __syncthreads();
    for (int off = 1; off < 512; off <<= 1) {
        int x = (t >= off) ? buf[t - off] : 0;
        __syncthreads();
        buf[t] += x;
        __syncthreads();
    }
    if (t < nb) { int e = buf[t] - v; bbase[t] = e; bcur[t] = e; }
    if (t == nb) bbase[nb] = buf[nb - 1];
    if (t == 0) rowptr[n] = etot;
}

__global__ __launch_bounds__(256) void k_bpart(const int* __restrict__ srcA,
                                               const int* __restrict__ dstA,
                                               int* __restrict__ bcur,
                                               unsigned* __restrict__ ebuf,
                                               int nE, int n) {
    __shared__ int cnt[512];
    __shared__ int run[512];
    int t = threadIdx.x;
    cnt[t] = 0; cnt[t + 256] = 0;
    __syncthreads();
    int tot = nE + n;
    int chunk = (tot + gridDim.x - 1) / gridDim.x;
    int c0 = blockIdx.x * chunk;
    int c1 = min(c0 + chunk, tot);
    for (int i = c0 + t; i < c1; i += 256) {
        int d = (i < nE) ? dstA[i] : (i - nE);
        atomicAdd(&cnt[d >> BSHIFT], 1);
    }
    __syncthreads();
    int c = cnt[t];
    if (c) run[t] = atomicAdd(&bcur[t], c);
    int c2 = cnt[t + 256];
    if (c2) run[t + 256] = atomicAdd(&bcur[t + 256], c2);
    __syncthreads();
    cnt[t] = 0; cnt[t + 256] = 0;
    __syncthreads();
    for (int i = c0 + t; i < c1; i += 256) {
        int s, d;
        if (i < nE) { s = srcA[i]; d = dstA[i]; }
        else        { s = d = i - nE; }
        int b = d >> BSHIFT;
        int pos = run[b] + atomicAdd(&cnt[b], 1);
        ebuf[pos] = ((unsigned)s << BSHIFT) | (unsigned)(d & (BSIZE - 1));
    }
}

__global__ __launch_bounds__(512) void k_bfill(const unsigned* __restrict__ ebuf,
                                               const int* __restrict__ bbase,
                                               int* __restrict__ rowptr,
                                               int* __restrict__ csr,
                                               int n, int nb) {
    int b = blockIdx.x;
    int lo = bbase[b], hi = bbase[b + 1];
    int cnt = hi - lo;
    int node0 = b << BSHIFT;
    __shared__ int deg[512];
    __shared__ int sbuf[512];
    __shared__ int cur[512];
    __shared__ unsigned stage[STAGE_CAP];
    int t = threadIdx.x;
    deg[t] = 0;
    __syncthreads();
    bool st = (cnt <= STAGE_CAP);
    for (int i = lo + t; i < hi; i += 512) {
        unsigned e = ebuf[i];
        if (st) stage[i - lo] = e;
        atomicAdd(&deg[e & (BSIZE - 1)], 1);
    }
    __syncthreads();
    int d = deg[t];
    sbuf[t] = d;
    __syncthreads();
    for (int off = 1; off < 512; off <<= 1) {
        int x = (t >= off) ? sbuf[t - off] : 0;
        __syncthreads();
        sbuf[t] += x;
        __syncthreads();
    }
    int excl = sbuf[t] - d;
    if (node0 + t < n) rowptr[node0 + t] = lo + excl;
    cur[t] = excl;
    __syncthreads();
    for (int i = lo + t; i < hi; i += 512) {
        unsigned e = st ? stage[i - lo] : ebuf[i];
        int pos = atomicAdd(&cur[e & (BSIZE - 1)], 1);
        csr[lo + pos] = (int)(e >> BSHIFT);
    }
}

// ---------------- GAT linear: xl = h@Wl+bl, xr = h@Wr+br ----------------

__global__ __launch_bounds__(256) void k_gat_gemm(
        const float* __restrict__ hin,
        const float* __restrict__ Wl, const float* __restrict__ bl,
        const float* __restrict__ Wr, const float* __restrict__ br,
        float* __restrict__ xl, float* __restrict__ xr, int n) {
    __shared__ float sWl[64 * 64];
    __shared__ float sWr[64 * 64];
    __shared__ float rows[4][64];
    int tid = threadIdx.x;
    for (int i = tid; i < 4096; i += 256) { sWl[i] = Wl[i]; sWr[i] = Wr[i]; }
    __syncthreads();
    int col = tid & 63, rl = tid >> 6;
    float blc = bl[col], brc = br[col];
    for (int r0 = blockIdx.x * 4; r0 < n; r0 += gridDim.x * 4) {
        int r = r0 + rl;
        rows[rl][col] = (r < n) ? hin[r * 64 + col] : 0.f;
        float al = blc, ar = brc;
        #pragma unroll
        for (int k = 0; k < 64; ++k) {
            float h = rows[rl][k];
            al = fmaf(h, sWl[k * 64 + col], al);
            ar = fmaf(h, sWr[k * 64 + col], ar);
        }
        if (r < n) { xl[r * 64 + col] = al; xr[r * 64 + col] = ar; }
    }
}

// ---------------- GAT edge aggregation (online softmax per dst) ----------------
// 8-wide predicated unroll: tail slots get p=-inf -> exp()=0 contribution.

__global__ __launch_bounds__(256) void k_gat_edge(
        const float* __restrict__ xl, const float* __restrict__ xr,
        const int* __restrict__ rowptr, const int* __restrict__ csr_src,
        const float* __restrict__ att, const float* __restrict__ bias,
        float* __restrict__ hout, int n, int do_relu) {
    int node = blockIdx.x * 4 + (threadIdx.x >> 6);
    if (node >= n) return;
    int lane = threadIdx.x & 63;
    float att_c = att[lane];
    float xr_c  = xr[node * 64 + lane];
    int beg = rowptr[node], end = rowptr[node + 1];
    float m = -INFINITY, s = 0.f, acc = 0.f;
    for (int k0 = beg; k0 < end; k0 += 8) {
        int idx[8]; float v[8], p[8];
        #pragma unroll
        for (int j = 0; j < 8; ++j) {
            int kk = k0 + j;
            idx[j] = csr_src[kk < end ? kk : end - 1];
        }
        #pragma unroll
        for (int j = 0; j < 8; ++j) v[j] = xl[(size_t)idx[j] * 64 + lane];
        #pragma unroll
        for (int j = 0; j < 8; ++j) {
            float tt = v[j] + xr_c;
            tt = (tt > 0.f) ? tt : 0.2f * tt;
            p[j] = tt * att_c;
        }
        #pragma unroll
        for (int off = 32; off; off >>= 1) {
            #pragma unroll
            for (int j = 0; j < 8; ++j) p[j] += __shfl_xor(p[j], off);
        }
        #pragma unroll
        for (int j = 0; j < 8; ++j) if (k0 + j >= end) p[j] = -INFINITY;
        float mx = m;
        #pragma unroll
        for (int j = 0; j < 8; ++j) mx = fmaxf(mx, p[j]);
        float sc = __expf(m - mx);
        float ws = 0.f, wa = 0.f;
        #pragma unroll
        for (int j = 0; j < 8; ++j) {
            float w = __expf(p[j] - mx);
            ws += w;
            wa = fmaf(w, v[j], wa);
        }
        s   = s * sc + ws;
        acc = acc * sc + wa;
        m = mx;
    }
    float o = acc / s + bias[lane];
    if (do_relu) o = fmaxf(o, 0.f);
    hout[node * 64 + lane] = o;
}

// ---------------- MLP GEMM (+ BN stats out; optional fused BN+ReLU on input) --

template <int DIN, int DOUT, int BN_IN>
__global__ __launch_bounds__(256) void k_mlp_gemm(
        const float* __restrict__ hin, const float* __restrict__ W,
        const float* __restrict__ bias, float* __restrict__ z,
        float* __restrict__ stat_sum, float* __restrict__ stat_sq,
        const float* __restrict__ muI, const float* __restrict__ ivI,
        const float* __restrict__ gI, const float* __restrict__ beI,
        int n, int do_stats) {
    constexpr int RP = 256 / DOUT;   // rows per iteration
    __shared__ float sW[DIN * DOUT];
    __shared__ float rows[RP][DIN];
    __shared__ float red[256];
    int tid = threadIdx.x;
    for (int i = tid; i < DIN * DOUT; i += 256) sW[i] = W[i];
    __syncthreads();
    int col = tid % DOUT, rl = tid / DOUT;
    float bc = bias[col];
    float lsum = 0.f, lsq = 0.f;
    for (int r0 = blockIdx.x * RP; r0 < n; r0 += gridDim.x * RP) {
        for (int i = tid; i < RP * DIN; i += 256) {
            int rr = r0 + i / DIN;
            int c = i % DIN;
            float v = (rr < n) ? hin[rr * DIN + c] : 0.f;
            if (BN_IN) {
                v = fmaxf(fmaf((v - muI[c]) * ivI[c], gI[c], beI[c]), 0.f);
            }
            rows[i / DIN][c] = v;
        }
        __syncthreads();
        int r = r0 + rl;
        float a = bc;
        #pragma unroll
        for (int k = 0; k < DIN; ++k) a = fmaf(rows[rl][k], sW[k * DOUT + col], a);
        if (r < n) {
            z[r * DOUT + col] = a;
            lsum += a;
            lsq  = fmaf(a, a, lsq);
        }
        __syncthreads();
    }
    if (do_stats) {
        red[tid] = lsum; __syncthreads();
        if (rl == 0) {
            float t = 0.f;
            for (int j = 0; j < RP; ++j) t += red[j * DOUT + col];
            atomicAdd(&stat_sum[col], t);
        }
        __syncthreads();
        red[tid] = lsq; __syncthreads();
        if (rl == 0) {
            float t = 0.f;
            for (int j = 0; j < RP; ++j) t += red[j * DOUT + col];
            atomicAdd(&stat_sq[col], t);
        }
    }
}

__global__ void k_bn_fin(const float* __restrict__ ssum, const float* __restrict__ ssq,
                         float* __restrict__ mu, float* __restrict__ inv,
                         int n, int dout) {
    int c = threadIdx.x;
    if (c >= dout) return;
    float m = ssum[c] / (float)n;
    float v = ssq[c] / (float)n - m * m;
    mu[c]  = m;
    inv[c] = rsqrtf(fmaxf(v, 0.f) + 1e-5f);
}

// ---------------- fused BN1+ReLU + final linear (64->1) + segmented mean-pool -

__global__ __launch_bounds__(256) void k_pool_seg(
        const float* __restrict__ h2, const float* __restrict__ w2,
        const float* __restrict__ b2, const int* __restrict__ batch,
        const float* __restrict__ mu1, const float* __restrict__ iv1,
        const float* __restrict__ g1, const float* __restrict__ be1,
        float* __restrict__ out, int n) {
    int g = blockIdx.x;
    int tid = threadIdx.x;
    int lo = 0, hi = n;
    while (lo < hi) { int mid = (lo + hi) >> 1; if (batch[mid] < g) lo = mid + 1; else hi = mid; }
    int start = lo;
    hi = n;
    while (lo < hi) { int mid = (lo + hi) >> 1; if (batch[mid] < g + 1) lo = mid + 1; else hi = mid; }
    int end = lo;
    int cnt = end - start;

    // per-thread fixed column block: bn(v)=v*A+B; out contrib = w2*max(bn,0)
    int c = (tid << 2) & 63;
    float A0 = iv1[c] * g1[c],         B0 = be1[c] - mu1[c] * A0;
    float A1 = iv1[c + 1] * g1[c + 1], B1 = be1[c + 1] - mu1[c + 1] * A1;
    float A2 = iv1[c + 2] * g1[c + 2], B2 = be1[c + 2] - mu1[c + 2] * A2;
    float A3 = iv1[c + 3] * g1[c + 3], B3 = be1[c + 3] - mu1[c + 3] * A3;
    float wa = w2[c], wb = w2[c + 1], wc = w2[c + 2], wd = w2[c + 3];
    const float4* b4 = reinterpret_cast<const float4*>(h2 + (size_t)start * 64);
    long total4 = (long)cnt * 16;
    float acc = 0.f;
    for (long i = tid; i < total4; i += 256) {
        float4 v = b4[i];
        acc = fmaf(fmaxf(fmaf(v.x, A0, B0), 0.f), wa, acc);
        acc = fmaf(fmaxf(fmaf(v.y, A1, B1), 0.f), wb, acc);
        acc = fmaf(fmaxf(fmaf(v.z, A2, B2), 0.f), wc, acc);
        acc = fmaf(fmaxf(fmaf(v.w, A3, B3), 0.f), wd, acc);
    }
    __shared__ float red[256];
    red[tid] = acc; __syncthreads();
    for (int off = 128; off; off >>= 1) {
        if (tid < off) red[tid] += red[tid + off];
        __syncthreads();
    }
    if (tid == 0) out[g] = (cnt > 0) ? red[0] / (float)cnt + b2[0] : 0.f;
}

// ---------------------------------------------------------------------------

extern "C" void kernel_launch(void* const* d_in, const int* in_sizes, int n_in,
                              void* d_out, int out_size, void* d_ws, size_t ws_size,
                              hipStream_t stream) {
    const float* x     = (const float*)d_in[0];
    const int*   ei    = (const int*)d_in[1];
    const int*   batch = (const int*)d_in[2];

    const int N = in_sizes[0] / 64;
    const int E = in_sizes[1] / 2;
    const int G = out_size;
    const int Etot = E + N;
    const int NB = (N + BSIZE - 1) >> BSHIFT;

    const int* srcA = ei;
    const int* dstA = ei + E;

    const float* Wl[3]; const float* bl[3]; const float* Wr[3];
    const float* br[3]; const float* att[3]; const float* bb[3];
    for (int l = 0; l < 3; ++l) {
        int base = 3 + 6 * l;
        Wl[l]  = (const float*)d_in[base + 0];
        bl[l]  = (const float*)d_in[base + 1];
        Wr[l]  = (const float*)d_in[base + 2];
        br[l]  = (const float*)d_in[base + 3];
        att[l] = (const float*)d_in[base + 4];
        bb[l]  = (const float*)d_in[base + 5];
    }
    const float* mW0 = (const float*)d_in[21];
    const float* mb0 = (const float*)d_in[22];
    const float* g0  = (const float*)d_in[23];
    const float* be0 = (const float*)d_in[24];
    const float* mW1 = (const float*)d_in[25];
    const float* mb1 = (const float*)d_in[26];
    const float* g1  = (const float*)d_in[27];
    const float* be1 = (const float*)d_in[28];
    const float* mW2 = (const float*)d_in[29];
    const float* mb2 = (const float*)d_in[30];

    // ---- workspace carve ----
    char* w = (char*)d_ws;
    auto alloc = [&](size_t bytes) -> void* {
        void* p = (void*)w;
        w += (bytes + 255) & ~(size_t)255;
        return p;
    };
    int*   rowptr = (int*)alloc((size_t)(N + 1) * 4);
    int*   csr    = (int*)alloc((size_t)Etot * 4);
    int*   bcnt   = (int*)alloc(512 * 4);
    int*   bbase  = (int*)alloc(520 * 4);
    int*   bcur   = (int*)alloc(512 * 4);
    float* xl     = (float*)alloc((size_t)N * 64 * 4); // xl+xr contiguous -> z
    float* xr     = (float*)alloc((size_t)N * 64 * 4);
    float* h      = (float*)alloc((size_t)N * 64 * 4);
    float* stats  = (float*)alloc(8 * 128 * 4);
    float* z      = xl;                                // [N,128] spans xl+xr
    unsigned* ebuf = (unsigned*)h;                     // dead before h is live

    float* sum0 = stats;        float* sq0 = stats + 128;
    float* mu0  = stats + 256;  float* iv0 = stats + 384;
    float* sum1 = stats + 512;  float* sq1 = stats + 640;
    float* mu1  = stats + 768;  float* iv1 = stats + 896;

    // ---- bucketed CSR build ----
    hipMemsetAsync(bcnt, 0, 512 * 4, stream);
    k_bcount<<<256, 256, 0, stream>>>(dstA, bcnt, E, N);
    k_bscan<<<1, 512, 0, stream>>>(bcnt, bbase, bcur, rowptr, NB, N, Etot);
    k_bpart<<<256, 256, 0, stream>>>(srcA, dstA, bcur, ebuf, E, N);
    k_bfill<<<NB, 512, 0, stream>>>(ebuf, bbase, rowptr, csr, N, NB);

    // ---- 3x GATv2 ----
    int nodeBlocks = (N + 3) / 4;
    const float* hin = x;
    for (int l = 0; l < 3; ++l) {
        k_gat_gemm<<<2048, 256, 0, stream>>>(hin, Wl[l], bl[l], Wr[l], br[l],
                                             xl, xr, N);
        k_gat_edge<<<nodeBlocks, 256, 0, stream>>>(xl, xr, rowptr, csr,
                                                   att[l], bb[l], h, N,
                                                   (l < 2) ? 1 : 0);
        hin = h;
    }

    // ---- MLP layer 0: 64 -> 128 (stats for BN0) ----
    hipMemsetAsync(sum0, 0, 2 * 128 * 4, stream);
    k_mlp_gemm<64, 128, 0><<<2048, 256, 0, stream>>>(
        h, mW0, mb0, z, sum0, sq0, nullptr, nullptr, nullptr, nullptr, N, 1);
    k_bn_fin<<<1, 128, 0, stream>>>(sum0, sq0, mu0, iv0, N, 128);

    // ---- MLP layer 1: 128 -> 64, BN0+ReLU fused into staging ----
    hipMemsetAsync(sum1, 0, 2 * 128 * 4, stream);
    k_mlp_gemm<128, 64, 1><<<2048, 256, 0, stream>>>(
        z, mW1, mb1, h, sum1, sq1, mu0, iv0, g0, be0, N, 1);
    k_bn_fin<<<1, 64, 0, stream>>>(sum1, sq1, mu1, iv1, N, 64);

    // ---- fused BN1+ReLU + final linear + segmented mean pool ----
    k_pool_seg<<<G, 256, 0, stream>>>(h, mW2, mb2, batch, mu1, iv1, g1, be1,
                                      (float*)d_out, N);
}

// Round 5
// 804.454 us; speedup vs baseline: 2.0445x; 1.0791x over previous
//
#include <hip/hip_runtime.h>
#include <hip/hip_bf16.h>
#include <hip/hip_fp16.h>
#include <math.h>

// ---------------------------------------------------------------------------
// MolGAT: 3x GATv2 (heads=1, D=64) + MLP(64->128->64->1, BN train-stats) +
// global mean pool over G=256 graphs.
// R4: bisect after replay-divergence in R3. GEMMs reverted to the exact
// replay-proven structures (868us run). Kept: bucketed CSR, BN fusion,
// 4-wide edge loop (968us-proven), and fp16 xl (deterministic change):
// edge gather table 25.6->12.8MB.
// ---------------------------------------------------------------------------

#define BSHIFT 9
#define BSIZE  512   // nodes per bucket
#define STAGE_CAP 24576

// ---------------- bucketed CSR build ----------------

__global__ __launch_bounds__(256) void k_bcount(const int* __restrict__ dstA,
                                                int* __restrict__ bcnt,
                                                int nE, int n) {
    __shared__ int h[512];
    int t = threadIdx.x;
    h[t] = 0; h[t + 256] = 0;
    __syncthreads();
    int tot = nE + n;
    for (int i = blockIdx.x * 256 + t; i < tot; i += gridDim.x * 256) {
        int d = (i < nE) ? dstA[i] : (i - nE);   // self loops appended
        atomicAdd(&h[d >> BSHIFT], 1);
    }
    __syncthreads();
    if (h[t])       atomicAdd(&bcnt[t], h[t]);
    if (h[t + 256]) atomicAdd(&bcnt[t + 256], h[t + 256]);
}

__global__ __launch_bounds__(512) void k_bscan(const int* __restrict__ bcnt,
                                               int* __restrict__ bbase,
                                               int* __restrict__ bcur,
                                               int* __restrict__ rowptr,
                                               int nb, int n, int etot) {
    __shared__ int buf[512];
    int t = threadIdx.x;
    int v = (t < nb) ? bcnt[t] : 0;
    buf[t] = v;
    __syncthreads();
    for (int off = 1; off < 512; off <<= 1) {
        int x = (t >= off) ? buf[t - off] : 0;
        __syncthreads();
        buf[t] += x;
        __syncthreads();
    }
    if (t < nb) { int e = buf[t] - v; bbase[t] = e; bcur[t] = e; }
    if (t == nb) bbase[nb] = buf[nb - 1];
    if (t == 0) rowptr[n] = etot;
}

__global__ __launch_bounds__(256) void k_bpart(const int* __restrict__ srcA,
                                               const int* __restrict__ dstA,
                                               int* __restrict__ bcur,
                                               unsigned* __restrict__ ebuf,
                                               int nE, int n) {
    __shared__ int cnt[512];
    __shared__ int run[512];
    int t = threadIdx.x;
    cnt[t] = 0; cnt[t + 256] = 0;
    __syncthreads();
    int tot = nE + n;
    int chunk = (tot + gridDim.x - 1) / gridDim.x;
    int c0 = blockIdx.x * chunk;
    int c1 = min(c0 + chunk, tot);
    for (int i = c0 + t; i < c1; i += 256) {
        int d = (i < nE) ? dstA[i] : (i - nE);
        atomicAdd(&cnt[d >> BSHIFT], 1);
    }
    __syncthreads();
    int c = cnt[t];
    if (c) run[t] = atomicAdd(&bcur[t], c);
    int c2 = cnt[t + 256];
    if (c2) run[t + 256] = atomicAdd(&bcur[t + 256], c2);
    __syncthreads();
    cnt[t] = 0; cnt[t + 256] = 0;
    __syncthreads();
    for (int i = c0 + t; i < c1; i += 256) {
        int s, d;
        if (i < nE) { s = srcA[i]; d = dstA[i]; }
        else        { s = d = i - nE; }
        int b = d >> BSHIFT;
        int pos = run[b] + atomicAdd(&cnt[b], 1);
        ebuf[pos] = ((unsigned)s << BSHIFT) | (unsigned)(d & (BSIZE - 1));
    }
}

__global__ __launch_bounds__(512) void k_bfill(const unsigned* __restrict__ ebuf,
                                               const int* __restrict__ bbase,
                                               int* __restrict__ rowptr,
                                               int* __restrict__ csr,
                                               int n, int nb) {
    int b = blockIdx.x;
    int lo = bbase[b], hi = bbase[b + 1];
    int cnt = hi - lo;
    int node0 = b << BSHIFT;
    __shared__ int deg[512];
    __shared__ int sbuf[512];
    __shared__ int cur[512];
    __shared__ unsigned stage[STAGE_CAP];
    int t = threadIdx.x;
    deg[t] = 0;
    __syncthreads();
    bool st = (cnt <= STAGE_CAP);
    for (int i = lo + t; i < hi; i += 512) {
        unsigned e = ebuf[i];
        if (st) stage[i - lo] = e;
        atomicAdd(&deg[e & (BSIZE - 1)], 1);
    }
    __syncthreads();
    int d = deg[t];
    sbuf[t] = d;
    __syncthreads();
    for (int off = 1; off < 512; off <<= 1) {
        int x = (t >= off) ? sbuf[t - off] : 0;
        __syncthreads();
        sbuf[t] += x;
        __syncthreads();
    }
    int excl = sbuf[t] - d;
    if (node0 + t < n) rowptr[node0 + t] = lo + excl;
    cur[t] = excl;
    __syncthreads();
    for (int i = lo + t; i < hi; i += 512) {
        unsigned e = st ? stage[i - lo] : ebuf[i];
        int pos = atomicAdd(&cur[e & (BSIZE - 1)], 1);
        csr[lo + pos] = (int)(e >> BSHIFT);
    }
}

// ---------------- GAT linear: xl(fp16) = h@Wl+bl, xr(fp32) = h@Wr+br --------
// replay-proven R2 structure; only the xl store changed to fp16.

__global__ __launch_bounds__(256) void k_gat_gemm(
        const float* __restrict__ hin,
        const float* __restrict__ Wl, const float* __restrict__ bl,
        const float* __restrict__ Wr, const float* __restrict__ br,
        __half* __restrict__ xl, float* __restrict__ xr, int n) {
    __shared__ float sWl[64 * 64];
    __shared__ float sWr[64 * 64];
    __shared__ float rows[4][64];
    int tid = threadIdx.x;
    for (int i = tid; i < 4096; i += 256) { sWl[i] = Wl[i]; sWr[i] = Wr[i]; }
    __syncthreads();
    int col = tid & 63, rl = tid >> 6;
    float blc = bl[col], brc = br[col];
    for (int r0 = blockIdx.x * 4; r0 < n; r0 += gridDim.x * 4) {
        int r = r0 + rl;
        rows[rl][col] = (r < n) ? hin[r * 64 + col] : 0.f;
        float al = blc, ar = brc;
        #pragma unroll
        for (int k = 0; k < 64; ++k) {
            float h = rows[rl][k];
            al = fmaf(h, sWl[k * 64 + col], al);
            ar = fmaf(h, sWr[k * 64 + col], ar);
        }
        if (r < n) {
            xl[r * 64 + col] = __float2half_rn(al);
            xr[r * 64 + col] = ar;
        }
    }
}

// ---------------- GAT edge aggregation (online softmax per dst) -------------
// 4-wide unroll + scalar tail (replay-proven); xl gathered as fp16.

__global__ __launch_bounds__(256) void k_gat_edge(
        const __half* __restrict__ xl, const float* __restrict__ xr,
        const int* __restrict__ rowptr, const int* __restrict__ csr_src,
        const float* __restrict__ att, const float* __restrict__ bias,
        float* __restrict__ hout, int n, int do_relu) {
    int node = blockIdx.x * 4 + (threadIdx.x >> 6);
    if (node >= n) return;
    int lane = threadIdx.x & 63;
    float att_c = att[lane];
    float xr_c  = xr[node * 64 + lane];
    int beg = rowptr[node], end = rowptr[node + 1];
    float m = -INFINITY, s = 0.f, acc = 0.f;
    int k = beg;
    for (; k + 4 <= end; k += 4) {
        int s0 = csr_src[k], s1 = csr_src[k + 1];
        int s2 = csr_src[k + 2], s3 = csr_src[k + 3];
        float v0 = __half2float(xl[(size_t)s0 * 64 + lane]);
        float v1 = __half2float(xl[(size_t)s1 * 64 + lane]);
        float v2 = __half2float(xl[(size_t)s2 * 64 + lane]);
        float v3 = __half2float(xl[(size_t)s3 * 64 + lane]);
        float t0 = v0 + xr_c; t0 = (t0 > 0.f) ? t0 : 0.2f * t0;
        float t1 = v1 + xr_c; t1 = (t1 > 0.f) ? t1 : 0.2f * t1;
        float t2 = v2 + xr_c; t2 = (t2 > 0.f) ? t2 : 0.2f * t2;
        float t3 = v3 + xr_c; t3 = (t3 > 0.f) ? t3 : 0.2f * t3;
        float p0 = t0 * att_c, p1 = t1 * att_c;
        float p2 = t2 * att_c, p3 = t3 * att_c;
        #pragma unroll
        for (int off = 32; off; off >>= 1) {
            p0 += __shfl_xor(p0, off);
            p1 += __shfl_xor(p1, off);
            p2 += __shfl_xor(p2, off);
            p3 += __shfl_xor(p3, off);
        }
        float mx = fmaxf(fmaxf(fmaxf(p0, p1), fmaxf(p2, p3)), m);
        float sc = __expf(m - mx);
        float w0 = __expf(p0 - mx), w1 = __expf(p1 - mx);
        float w2 = __expf(p2 - mx), w3 = __expf(p3 - mx);
        s   = s * sc + ((w0 + w1) + (w2 + w3));
        acc = acc * sc + fmaf(w0, v0, fmaf(w1, v1, fmaf(w2, v2, w3 * v3)));
        m = mx;
    }
    for (; k < end; ++k) {
        int src = csr_src[k];
        float v = __half2float(xl[(size_t)src * 64 + lane]);
        float t = v + xr_c;
        t = (t > 0.f) ? t : 0.2f * t;
        float p = t * att_c;
        #pragma unroll
        for (int off = 32; off; off >>= 1) p += __shfl_xor(p, off);
        float mn = fmaxf(m, p);
        float sc = __expf(m - mn);
        float w  = __expf(p - mn);
        s   = s * sc + w;
        acc = acc * sc + w * v;
        m = mn;
    }
    float o = acc / s + bias[lane];
    if (do_relu) o = fmaxf(o, 0.f);
    hout[node * 64 + lane] = o;
}

// ---------------- MLP GEMM (replay-proven structure; optional BN_IN fusion) --

template <int DIN, int DOUT, int BN_IN>
__global__ __launch_bounds__(256) void k_mlp_gemm(
        const float* __restrict__ hin, const float* __restrict__ W,
        const float* __restrict__ bias, float* __restrict__ z,
        float* __restrict__ stat_sum, float* __restrict__ stat_sq,
        const float* __restrict__ muI, const float* __restrict__ ivI,
        const float* __restrict__ gI, const float* __restrict__ beI,
        int n, int do_stats) {
    constexpr int RP = 256 / DOUT;   // rows per iteration
    __shared__ float sW[DIN * DOUT];
    __shared__ float rows[RP][DIN];
    __shared__ float red[256];
    __shared__ float sA[128], sB[128];
    int tid = threadIdx.x;
    for (int i = tid; i < DIN * DOUT; i += 256) sW[i] = W[i];
    if (BN_IN && tid < DIN) {
        float a = ivI[tid] * gI[tid];
        sA[tid] = a;
        sB[tid] = beI[tid] - muI[tid] * a;
    }
    __syncthreads();
    int col = tid % DOUT, rl = tid / DOUT;
    float bc = bias[col];
    float lsum = 0.f, lsq = 0.f;
    for (int r0 = blockIdx.x * RP; r0 < n; r0 += gridDim.x * RP) {
        for (int i = tid; i < RP * DIN; i += 256) {
            int rr = r0 + i / DIN;
            int c = i % DIN;
            float v = (rr < n) ? hin[(size_t)rr * DIN + c] : 0.f;
            if (BN_IN) {
                v = fmaxf(fmaf(v, sA[c], sB[c]), 0.f);
            }
            rows[i / DIN][c] = v;
        }
        __syncthreads();
        int r = r0 + rl;
        float a = bc;
        #pragma unroll
        for (int k = 0; k < DIN; ++k) a = fmaf(rows[rl][k], sW[k * DOUT + col], a);
        if (r < n) {
            z[(size_t)r * DOUT + col] = a;
            lsum += a;
            lsq  = fmaf(a, a, lsq);
        }
        __syncthreads();
    }
    if (do_stats) {
        red[tid] = lsum; __syncthreads();
        if (rl == 0) {
            float t = 0.f;
            for (int j = 0; j < RP; ++j) t += red[j * DOUT + col];
            atomicAdd(&stat_sum[col], t);
        }
        __syncthreads();
        red[tid] = lsq; __syncthreads();
        if (rl == 0) {
            float t = 0.f;
            for (int j = 0; j < RP; ++j) t += red[j * DOUT + col];
            atomicAdd(&stat_sq[col], t);
        }
    }
}

__global__ void k_bn_fin(const float* __restrict__ ssum, const float* __restrict__ ssq,
                         float* __restrict__ mu, float* __restrict__ inv,
                         int n, int dout) {
    int c = threadIdx.x;
    if (c >= dout) return;
    float m = ssum[c] / (float)n;
    float v = ssq[c] / (float)n - m * m;
    mu[c]  = m;
    inv[c] = rsqrtf(fmaxf(v, 0.f) + 1e-5f);
}

// ---------------- fused BN1+ReLU + final linear (64->1) + segmented mean-pool -

__global__ __launch_bounds__(256) void k_pool_seg(
        const float* __restrict__ h2, const float* __restrict__ w2,
        const float* __restrict__ b2, const int* __restrict__ batch,
        const float* __restrict__ mu1, const float* __restrict__ iv1,
        const float* __restrict__ g1, const float* __restrict__ be1,
        float* __restrict__ out, int n) {
    int g = blockIdx.x;
    int tid = threadIdx.x;
    int lo = 0, hi = n;
    while (lo < hi) { int mid = (lo + hi) >> 1; if (batch[mid] < g) lo = mid + 1; else hi = mid; }
    int start = lo;
    hi = n;
    while (lo < hi) { int mid = (lo + hi) >> 1; if (batch[mid] < g + 1) lo = mid + 1; else hi = mid; }
    int end = lo;
    int cnt = end - start;

    int c = (tid << 2) & 63;
    float A0 = iv1[c] * g1[c],         B0 = be1[c] - mu1[c] * A0;
    float A1 = iv1[c + 1] * g1[c + 1], B1 = be1[c + 1] - mu1[c + 1] * A1;
    float A2 = iv1[c + 2] * g1[c + 2], B2 = be1[c + 2] - mu1[c + 2] * A2;
    float A3 = iv1[c + 3] * g1[c + 3], B3 = be1[c + 3] - mu1[c + 3] * A3;
    float wa = w2[c], wb = w2[c + 1], wc = w2[c + 2], wd = w2[c + 3];
    const float4* b4 = reinterpret_cast<const float4*>(h2 + (size_t)start * 64);
    long total4 = (long)cnt * 16;
    float acc = 0.f;
    for (long i = tid; i < total4; i += 256) {
        float4 v = b4[i];
        acc = fmaf(fmaxf(fmaf(v.x, A0, B0), 0.f), wa, acc);
        acc = fmaf(fmaxf(fmaf(v.y, A1, B1), 0.f), wb, acc);
        acc = fmaf(fmaxf(fmaf(v.z, A2, B2), 0.f), wc, acc);
        acc = fmaf(fmaxf(fmaf(v.w, A3, B3), 0.f), wd, acc);
    }
    __shared__ float red[256];
    red[tid] = acc; __syncthreads();
    for (int off = 128; off; off >>= 1) {
        if (tid < off) red[tid] += red[tid + off];
        __syncthreads();
    }
    if (tid == 0) out[g] = (cnt > 0) ? red[0] / (float)cnt + b2[0] : 0.f;
}

// ---------------------------------------------------------------------------

extern "C" void kernel_launch(void* const* d_in, const int* in_sizes, int n_in,
                              void* d_out, int out_size, void* d_ws, size_t ws_size,
                              hipStream_t stream) {
    const float* x     = (const float*)d_in[0];
    const int*   ei    = (const int*)d_in[1];
    const int*   batch = (const int*)d_in[2];

    const int N = in_sizes[0] / 64;
    const int E = in_sizes[1] / 2;
    const int G = out_size;
    const int Etot = E + N;
    const int NB = (N + BSIZE - 1) >> BSHIFT;

    const int* srcA = ei;
    const int* dstA = ei + E;

    const float* Wl[3]; const float* bl[3]; const float* Wr[3];
    const float* br[3]; const float* att[3]; const float* bb[3];
    for (int l = 0; l < 3; ++l) {
        int base = 3 + 6 * l;
        Wl[l]  = (const float*)d_in[base + 0];
        bl[l]  = (const float*)d_in[base + 1];
        Wr[l]  = (const float*)d_in[base + 2];
        br[l]  = (const float*)d_in[base + 3];
        att[l] = (const float*)d_in[base + 4];
        bb[l]  = (const float*)d_in[base + 5];
    }
    const float* mW0 = (const float*)d_in[21];
    const float* mb0 = (const float*)d_in[22];
    const float* g0  = (const float*)d_in[23];
    const float* be0 = (const float*)d_in[24];
    const float* mW1 = (const float*)d_in[25];
    const float* mb1 = (const float*)d_in[26];
    const float* g1  = (const float*)d_in[27];
    const float* be1 = (const float*)d_in[28];
    const float* mW2 = (const float*)d_in[29];
    const float* mb2 = (const float*)d_in[30];

    // ---- workspace carve ----
    char* w = (char*)d_ws;
    auto alloc = [&](size_t bytes) -> void* {
        void* p = (void*)w;
        w += (bytes + 255) & ~(size_t)255;
        return p;
    };
    int*    rowptr = (int*)alloc((size_t)(N + 1) * 4);
    int*    csr    = (int*)alloc((size_t)Etot * 4);
    int*    bcnt   = (int*)alloc(512 * 4);
    int*    bbase  = (int*)alloc(520 * 4);
    int*    bcur   = (int*)alloc(512 * 4);
    // xl(half,12.8MB) + xr(f32,25.6MB) + zext(12.8MB) contiguous; z spans them
    __half* xl     = (__half*)alloc((size_t)N * 64 * 2);
    float*  xr     = (float*)alloc((size_t)N * 64 * 4);
    float*  zext   = (float*)alloc((size_t)N * 32 * 4);
    float*  h      = (float*)alloc((size_t)N * 64 * 4);
    float*  stats  = (float*)alloc(8 * 128 * 4);
    float*  z      = (float*)xl;          // [N,128] fp32 spans xl+xr+zext
    unsigned* ebuf = (unsigned*)h;        // dead before h is live
    (void)zext;

    float* sum0 = stats;        float* sq0 = stats + 128;
    float* mu0  = stats + 256;  float* iv0 = stats + 384;
    float* sum1 = stats + 512;  float* sq1 = stats + 640;
    float* mu1  = stats + 768;  float* iv1 = stats + 896;

    // ---- bucketed CSR build ----
    hipMemsetAsync(bcnt, 0, 512 * 4, stream);
    k_bcount<<<256, 256, 0, stream>>>(dstA, bcnt, E, N);
    k_bscan<<<1, 512, 0, stream>>>(bcnt, bbase, bcur, rowptr, NB, N, Etot);
    k_bpart<<<256, 256, 0, stream>>>(srcA, dstA, bcur, ebuf, E, N);
    k_bfill<<<NB, 512, 0, stream>>>(ebuf, bbase, rowptr, csr, N, NB);

    // ---- 3x GATv2 ----
    int nodeBlocks = (N + 3) / 4;
    const float* hin = x;
    for (int l = 0; l < 3; ++l) {
        k_gat_gemm<<<2048, 256, 0, stream>>>(hin, Wl[l], bl[l], Wr[l], br[l],
                                             xl, xr, N);
        k_gat_edge<<<nodeBlocks, 256, 0, stream>>>(xl, xr, rowptr, csr,
                                                   att[l], bb[l], h, N,
                                                   (l < 2) ? 1 : 0);
        hin = h;
    }

    // ---- MLP layer 0: 64 -> 128 (stats for BN0) ----
    hipMemsetAsync(sum0, 0, 2 * 128 * 4, stream);
    k_mlp_gemm<64, 128, 0><<<2048, 256, 0, stream>>>(
        h, mW0, mb0, z, sum0, sq0, nullptr, nullptr, nullptr, nullptr, N, 1);
    k_bn_fin<<<1, 128, 0, stream>>>(sum0, sq0, mu0, iv0, N, 128);

    // ---- MLP layer 1: 128 -> 64, BN0+ReLU fused into staging ----
    hipMemsetAsync(sum1, 0, 2 * 128 * 4, stream);
    k_mlp_gemm<128, 64, 1><<<2048, 256, 0, stream>>>(
        z, mW1, mb1, h, sum1, sq1, mu0, iv0, g0, be0, N, 1);
    k_bn_fin<<<1, 64, 0, stream>>>(sum1, sq1, mu1, iv1, N, 64);

    // ---- fused BN1+ReLU + final linear + segmented mean pool ----
    k_pool_seg<<<G, 256, 0, stream>>>(h, mW2, mb2, batch, mu1, iv1, g1, be1,
                                      (float*)d_out, N);
}

// Round 6
// 576.214 us; speedup vs baseline: 2.8543x; 1.3961x over previous
//
#include <hip/hip_runtime.h>
#include <hip/hip_bf16.h>
#include <hip/hip_fp16.h>
#include <math.h>

// ---------------------------------------------------------------------------
// MolGAT: 3x GATv2 (heads=1, D=64) + MLP(64->128->64->1, BN train-stats) +
// global mean pool over G=256 graphs.
// R5: (a) group-parallel edge kernel: wave=node, 4x16-lane groups each own an
//     edge, lane owns 4 channels (fp16x4 load). 8 shuffles/4 edges vs 24 —
//     old kernel was VALU+DS-pipe bound (VALUBusy 70%, hbm 13%).
//     (b) register-weight GEMMs (barriered stage->sync->consume): weights in
//     VGPRs, rows via wave-uniform float4 LDS broadcast; replaces the
//     3-ds_read-per-2fma structure (~300us across 5 GEMM dispatches).
// ---------------------------------------------------------------------------

#define BSHIFT 9
#define BSIZE  512   // nodes per bucket
#define STAGE_CAP 24576

// ---------------- bucketed CSR build (unchanged, replay-proven) ----------------

__global__ __launch_bounds__(256) void k_bcount(const int* __restrict__ dstA,
                                                int* __restrict__ bcnt,
                                                int nE, int n) {
    __shared__ int h[512];
    int t = threadIdx.x;
    h[t] = 0; h[t + 256] = 0;
    __syncthreads();
    int tot = nE + n;
    for (int i = blockIdx.x * 256 + t; i < tot; i += gridDim.x * 256) {
        int d = (i < nE) ? dstA[i] : (i - nE);   // self loops appended
        atomicAdd(&h[d >> BSHIFT], 1);
    }
    __syncthreads();
    if (h[t])       atomicAdd(&bcnt[t], h[t]);
    if (h[t + 256]) atomicAdd(&bcnt[t + 256], h[t + 256]);
}

__global__ __launch_bounds__(512) void k_bscan(const int* __restrict__ bcnt,
                                               int* __restrict__ bbase,
                                               int* __restrict__ bcur,
                                               int* __restrict__ rowptr,
                                               int nb, int n, int etot) {
    __shared__ int buf[512];
    int t = threadIdx.x;
    int v = (t < nb) ? bcnt[t] : 0;
    buf[t] = v;
    __syncthreads();
    for (int off = 1; off < 512; off <<= 1) {
        int x = (t >= off) ? buf[t - off] : 0;
        __syncthreads();
        buf[t] += x;
        __syncthreads();
    }
    if (t < nb) { int e = buf[t] - v; bbase[t] = e; bcur[t] = e; }
    if (t == nb) bbase[nb] = buf[nb - 1];
    if (t == 0) rowptr[n] = etot;
}

__global__ __launch_bounds__(256) void k_bpart(const int* __restrict__ srcA,
                                               const int* __restrict__ dstA,
                                               int* __restrict__ bcur,
                                               unsigned* __restrict__ ebuf,
                                               int nE, int n) {
    __shared__ int cnt[512];
    __shared__ int run[512];
    int t = threadIdx.x;
    cnt[t] = 0; cnt[t + 256] = 0;
    __syncthreads();
    int tot = nE + n;
    int chunk = (tot + gridDim.x - 1) / gridDim.x;
    int c0 = blockIdx.x * chunk;
    int c1 = min(c0 + chunk, tot);
    for (int i = c0 + t; i < c1; i += 256) {
        int d = (i < nE) ? dstA[i] : (i - nE);
        atomicAdd(&cnt[d >> BSHIFT], 1);
    }
    __syncthreads();
    int c = cnt[t];
    if (c) run[t] = atomicAdd(&bcur[t], c);
    int c2 = cnt[t + 256];
    if (c2) run[t + 256] = atomicAdd(&bcur[t + 256], c2);
    __syncthreads();
    cnt[t] = 0; cnt[t + 256] = 0;
    __syncthreads();
    for (int i = c0 + t; i < c1; i += 256) {
        int s, d;
        if (i < nE) { s = srcA[i]; d = dstA[i]; }
        else        { s = d = i - nE; }
        int b = d >> BSHIFT;
        int pos = run[b] + atomicAdd(&cnt[b], 1);
        ebuf[pos] = ((unsigned)s << BSHIFT) | (unsigned)(d & (BSIZE - 1));
    }
}

__global__ __launch_bounds__(512) void k_bfill(const unsigned* __restrict__ ebuf,
                                               const int* __restrict__ bbase,
                                               int* __restrict__ rowptr,
                                               int* __restrict__ csr,
                                               int n, int nb) {
    int b = blockIdx.x;
    int lo = bbase[b], hi = bbase[b + 1];
    int cnt = hi - lo;
    int node0 = b << BSHIFT;
    __shared__ int deg[512];
    __shared__ int sbuf[512];
    __shared__ int cur[512];
    __shared__ unsigned stage[STAGE_CAP];
    int t = threadIdx.x;
    deg[t] = 0;
    __syncthreads();
    bool st = (cnt <= STAGE_CAP);
    for (int i = lo + t; i < hi; i += 512) {
        unsigned e = ebuf[i];
        if (st) stage[i - lo] = e;
        atomicAdd(&deg[e & (BSIZE - 1)], 1);
    }
    __syncthreads();
    int d = deg[t];
    sbuf[t] = d;
    __syncthreads();
    for (int off = 1; off < 512; off <<= 1) {
        int x = (t >= off) ? sbuf[t - off] : 0;
        __syncthreads();
        sbuf[t] += x;
        __syncthreads();
    }
    int excl = sbuf[t] - d;
    if (node0 + t < n) rowptr[node0 + t] = lo + excl;
    cur[t] = excl;
    __syncthreads();
    for (int i = lo + t; i < hi; i += 512) {
        unsigned e = st ? stage[i - lo] : ebuf[i];
        int pos = atomicAdd(&cur[e & (BSIZE - 1)], 1);
        csr[lo + pos] = (int)(e >> BSHIFT);
    }
}

// ---------------- GAT linear: xl(fp16) = h@Wl+bl, xr(fp32) = h@Wr+br --------
// Register-resident weights (64+64 VGPR); rows staged 16/tile, consumed as
// wave-uniform float4 broadcasts. Barriered stage->consume.

__global__ __launch_bounds__(256) void k_gat_gemm(
        const float* __restrict__ hin,
        const float* __restrict__ Wl, const float* __restrict__ bl,
        const float* __restrict__ Wr, const float* __restrict__ br,
        __half* __restrict__ xl, float* __restrict__ xr, int n) {
    __shared__ float rows[16][64];
    int tid = threadIdx.x;
    int col = tid & 63, rlane = tid >> 6;
    float wlr[64], wrr[64];
    #pragma unroll
    for (int k = 0; k < 64; ++k) {
        wlr[k] = Wl[k * 64 + col];
        wrr[k] = Wr[k * 64 + col];
    }
    float blc = bl[col], brc = br[col];
    int sr = tid >> 4, sc4 = (tid & 15) << 2;
    for (int r0 = blockIdx.x * 16; r0 < n; r0 += gridDim.x * 16) {
        int rr = r0 + sr;
        float4 v = make_float4(0.f, 0.f, 0.f, 0.f);
        if (rr < n) v = *reinterpret_cast<const float4*>(hin + (size_t)rr * 64 + sc4);
        *reinterpret_cast<float4*>(&rows[sr][sc4]) = v;
        __syncthreads();
        #pragma unroll
        for (int q = 0; q < 4; ++q) {
            int rI = rlane * 4 + q;
            int r = r0 + rI;
            float al = blc, ar = brc;
            const float4* rv = reinterpret_cast<const float4*>(rows[rI]);
            #pragma unroll
            for (int k4 = 0; k4 < 16; ++k4) {
                float4 h4 = rv[k4];
                al = fmaf(h4.x, wlr[k4 * 4 + 0], al); ar = fmaf(h4.x, wrr[k4 * 4 + 0], ar);
                al = fmaf(h4.y, wlr[k4 * 4 + 1], al); ar = fmaf(h4.y, wrr[k4 * 4 + 1], ar);
                al = fmaf(h4.z, wlr[k4 * 4 + 2], al); ar = fmaf(h4.z, wrr[k4 * 4 + 2], ar);
                al = fmaf(h4.w, wlr[k4 * 4 + 3], al); ar = fmaf(h4.w, wrr[k4 * 4 + 3], ar);
            }
            if (r < n) {
                xl[r * 64 + col] = __float2half_rn(al);
                xr[(size_t)r * 64 + col] = ar;
            }
        }
        __syncthreads();
    }
}

// ---------------- GAT edge aggregation (group-parallel online softmax) ------
// wave = 1 node; 4 groups of 16 lanes each own one edge; lane owns 4 channels.

__global__ __launch_bounds__(256) void k_gat_edge(
        const __half* __restrict__ xl, const float* __restrict__ xr,
        const int* __restrict__ rowptr, const int* __restrict__ csr_src,
        const float* __restrict__ att, const float* __restrict__ bias,
        float* __restrict__ hout, int n, int do_relu) {
    int node = blockIdx.x * 4 + (threadIdx.x >> 6);
    if (node >= n) return;
    int lane = threadIdx.x & 63;
    int grp = lane >> 4, sub = lane & 15;
    int c0 = sub << 2;
    float4 attv = *reinterpret_cast<const float4*>(att + c0);
    float4 xrv  = *reinterpret_cast<const float4*>(xr + (size_t)node * 64 + c0);
    int beg = rowptr[node], end = rowptr[node + 1];
    float m = -INFINITY, s = 0.f;
    float acc0 = 0.f, acc1 = 0.f, acc2 = 0.f, acc3 = 0.f;
    for (int k0 = beg; k0 < end; k0 += 4) {
        int kk = k0 + grp;
        int idx = csr_src[kk < end ? kk : end - 1];
        uint2 raw = *reinterpret_cast<const uint2*>(xl + ((size_t)idx << 6) + c0);
        float2 f01 = __half22float2(*reinterpret_cast<__half2*>(&raw.x));
        float2 f23 = __half22float2(*reinterpret_cast<__half2*>(&raw.y));
        float v0 = f01.x, v1 = f01.y, v2 = f23.x, v3 = f23.y;
        float t0 = v0 + xrv.x; t0 = (t0 > 0.f) ? t0 : 0.2f * t0;
        float t1 = v1 + xrv.y; t1 = (t1 > 0.f) ? t1 : 0.2f * t1;
        float t2 = v2 + xrv.z; t2 = (t2 > 0.f) ? t2 : 0.2f * t2;
        float t3 = v3 + xrv.w; t3 = (t3 > 0.f) ? t3 : 0.2f * t3;
        float p = fmaf(t3, attv.w, fmaf(t2, attv.z, fmaf(t1, attv.y, t0 * attv.x)));
        // dot reduce within 16-lane group
        p += __shfl_xor(p, 1);
        p += __shfl_xor(p, 2);
        p += __shfl_xor(p, 4);
        p += __shfl_xor(p, 8);
        // broadcast all 4 group dots to every lane
        float p0 = __shfl(p, sub);
        float p1 = __shfl(p, 16 + sub);
        float p2 = __shfl(p, 32 + sub);
        float p3 = __shfl(p, 48 + sub);
        int rem = end - k0;
        if (rem < 4) {
            if (rem <= 1) p1 = -INFINITY;
            if (rem <= 2) p2 = -INFINITY;
            if (rem <= 3) p3 = -INFINITY;
        }
        float mx = fmaxf(fmaxf(fmaxf(p0, p1), fmaxf(p2, p3)), m);
        float sc = __expf(m - mx);
        float w0 = __expf(p0 - mx), w1 = __expf(p1 - mx);
        float w2 = __expf(p2 - mx), w3 = __expf(p3 - mx);
        float wm = (grp < 2) ? ((grp == 0) ? w0 : w1) : ((grp == 2) ? w2 : w3);
        s = s * sc + ((w0 + w1) + (w2 + w3));
        acc0 = fmaf(wm, v0, acc0 * sc);
        acc1 = fmaf(wm, v1, acc1 * sc);
        acc2 = fmaf(wm, v2, acc2 * sc);
        acc3 = fmaf(wm, v3, acc3 * sc);
        m = mx;
    }
    // merge the 4 group accumulators (same channels live in lanes sub+16g)
    acc0 += __shfl_xor(acc0, 16); acc0 += __shfl_xor(acc0, 32);
    acc1 += __shfl_xor(acc1, 16); acc1 += __shfl_xor(acc1, 32);
    acc2 += __shfl_xor(acc2, 16); acc2 += __shfl_xor(acc2, 32);
    acc3 += __shfl_xor(acc3, 16); acc3 += __shfl_xor(acc3, 32);
    float inv = 1.0f / s;
    float4 bv = *reinterpret_cast<const float4*>(bias + c0);
    float o0 = fmaf(acc0, inv, bv.x);
    float o1 = fmaf(acc1, inv, bv.y);
    float o2 = fmaf(acc2, inv, bv.z);
    float o3 = fmaf(acc3, inv, bv.w);
    if (do_relu) {
        o0 = fmaxf(o0, 0.f); o1 = fmaxf(o1, 0.f);
        o2 = fmaxf(o2, 0.f); o3 = fmaxf(o3, 0.f);
    }
    if (grp == 0) {
        *reinterpret_cast<float4*>(hout + (size_t)node * 64 + c0) =
            make_float4(o0, o1, o2, o3);
    }
}

// ---------------- MLP GEMM: register weights, staged rows, BN stats ---------

template <int DIN, int DOUT, int BN_IN>
__global__ __launch_bounds__(256) void k_mlp_gemm(
        const float* __restrict__ hin, const float* __restrict__ W,
        const float* __restrict__ bias, float* __restrict__ z,
        float* __restrict__ stat_sum, float* __restrict__ stat_sq,
        const float* __restrict__ muI, const float* __restrict__ ivI,
        const float* __restrict__ gI, const float* __restrict__ beI,
        int n) {
    constexpr int COLS = DOUT / 64;          // outputs per thread (1 or 2)
    constexpr int F4PT = DIN / 64;           // staging float4s per thread (1 or 2)
    __shared__ float rows[16][DIN];
    __shared__ float red[256];
    int tid = threadIdx.x;
    int col = tid & 63, rlane = tid >> 6;
    float wreg[COLS][DIN];
    #pragma unroll
    for (int j = 0; j < COLS; ++j)
        #pragma unroll
        for (int k = 0; k < DIN; ++k)
            wreg[j][k] = W[k * DOUT + col + j * 64];
    float bc[COLS], ls[COLS], lq[COLS];
    #pragma unroll
    for (int j = 0; j < COLS; ++j) {
        bc[j] = bias[col + j * 64];
        ls[j] = 0.f; lq[j] = 0.f;
    }
    // staging geometry + optional BN coeffs for the staged columns
    int srT[F4PT], scT[F4PT];
    float4 An[F4PT], Bn[F4PT];
    #pragma unroll
    for (int i = 0; i < F4PT; ++i) {
        int idx = tid + i * 256;
        srT[i] = idx / (DIN / 4);
        scT[i] = (idx % (DIN / 4)) * 4;
        if (BN_IN) {
            int c = scT[i];
            float4 iv4 = *reinterpret_cast<const float4*>(ivI + c);
            float4 g4  = *reinterpret_cast<const float4*>(gI + c);
            float4 mu4 = *reinterpret_cast<const float4*>(muI + c);
            float4 be4 = *reinterpret_cast<const float4*>(beI + c);
            An[i].x = iv4.x * g4.x; Bn[i].x = be4.x - mu4.x * An[i].x;
            An[i].y = iv4.y * g4.y; Bn[i].y = be4.y - mu4.y * An[i].y;
            An[i].z = iv4.z * g4.z; Bn[i].z = be4.z - mu4.z * An[i].z;
            An[i].w = iv4.w * g4.w; Bn[i].w = be4.w - mu4.w * An[i].w;
        }
    }
    for (int r0 = blockIdx.x * 16; r0 < n; r0 += gridDim.x * 16) {
        #pragma unroll
        for (int i = 0; i < F4PT; ++i) {
            int rr = r0 + srT[i];
            float4 v = make_float4(0.f, 0.f, 0.f, 0.f);
            if (rr < n) v = *reinterpret_cast<const float4*>(hin + (size_t)rr * DIN + scT[i]);
            if (BN_IN) {
                v.x = fmaxf(fmaf(v.x, An[i].x, Bn[i].x), 0.f);
                v.y = fmaxf(fmaf(v.y, An[i].y, Bn[i].y), 0.f);
                v.z = fmaxf(fmaf(v.z, An[i].z, Bn[i].z), 0.f);
                v.w = fmaxf(fmaf(v.w, An[i].w, Bn[i].w), 0.f);
            }
            *reinterpret_cast<float4*>(&rows[srT[i]][scT[i]]) = v;
        }
        __syncthreads();
        #pragma unroll
        for (int q = 0; q < 4; ++q) {
            int rI = rlane * 4 + q;
            int r = r0 + rI;
            float a[COLS];
            #pragma unroll
            for (int j = 0; j < COLS; ++j) a[j] = bc[j];
            const float4* rv = reinterpret_cast<const float4*>(rows[rI]);
            #pragma unroll
            for (int k4 = 0; k4 < DIN / 4; ++k4) {
                float4 h4 = rv[k4];
                #pragma unroll
                for (int j = 0; j < COLS; ++j) {
                    a[j] = fmaf(h4.x, wreg[j][k4 * 4 + 0], a[j]);
                    a[j] = fmaf(h4.y, wreg[j][k4 * 4 + 1], a[j]);
                    a[j] = fmaf(h4.z, wreg[j][k4 * 4 + 2], a[j]);
                    a[j] = fmaf(h4.w, wreg[j][k4 * 4 + 3], a[j]);
                }
            }
            if (r < n) {
                #pragma unroll
                for (int j = 0; j < COLS; ++j) {
                    z[(size_t)r * DOUT + col + j * 64] = a[j];
                    ls[j] += a[j];
                    lq[j] = fmaf(a[j], a[j], lq[j]);
                }
            }
        }
        __syncthreads();
    }
    // block reduce of BN stats: 4 row-lanes share each column
    #pragma unroll
    for (int j = 0; j < COLS; ++j) {
        __syncthreads();
        red[tid] = ls[j];
        __syncthreads();
        if (rlane == 0) {
            float t = red[col] + red[col + 64] + red[col + 128] + red[col + 192];
            atomicAdd(&stat_sum[col + j * 64], t);
        }
        __syncthreads();
        red[tid] = lq[j];
        __syncthreads();
        if (rlane == 0) {
            float t = red[col] + red[col + 64] + red[col + 128] + red[col + 192];
            atomicAdd(&stat_sq[col + j * 64], t);
        }
    }
}

__global__ void k_bn_fin(const float* __restrict__ ssum, const float* __restrict__ ssq,
                         float* __restrict__ mu, float* __restrict__ inv,
                         int n, int dout) {
    int c = threadIdx.x;
    if (c >= dout) return;
    float m = ssum[c] / (float)n;
    float v = ssq[c] / (float)n - m * m;
    mu[c]  = m;
    inv[c] = rsqrtf(fmaxf(v, 0.f) + 1e-5f);
}

// ---------------- fused BN1+ReLU + final linear (64->1) + segmented mean-pool -

__global__ __launch_bounds__(256) void k_pool_seg(
        const float* __restrict__ h2, const float* __restrict__ w2,
        const float* __restrict__ b2, const int* __restrict__ batch,
        const float* __restrict__ mu1, const float* __restrict__ iv1,
        const float* __restrict__ g1, const float* __restrict__ be1,
        float* __restrict__ out, int n) {
    int g = blockIdx.x;
    int tid = threadIdx.x;
    int lo = 0, hi = n;
    while (lo < hi) { int mid = (lo + hi) >> 1; if (batch[mid] < g) lo = mid + 1; else hi = mid; }
    int start = lo;
    hi = n;
    while (lo < hi) { int mid = (lo + hi) >> 1; if (batch[mid] < g + 1) lo = mid + 1; else hi = mid; }
    int end = lo;
    int cnt = end - start;

    int c = (tid << 2) & 63;
    float A0 = iv1[c] * g1[c],         B0 = be1[c] - mu1[c] * A0;
    float A1 = iv1[c + 1] * g1[c + 1], B1 = be1[c + 1] - mu1[c + 1] * A1;
    float A2 = iv1[c + 2] * g1[c + 2], B2 = be1[c + 2] - mu1[c + 2] * A2;
    float A3 = iv1[c + 3] * g1[c + 3], B3 = be1[c + 3] - mu1[c + 3] * A3;
    float wa = w2[c], wb = w2[c + 1], wc = w2[c + 2], wd = w2[c + 3];
    const float4* b4 = reinterpret_cast<const float4*>(h2 + (size_t)start * 64);
    long total4 = (long)cnt * 16;
    float acc = 0.f;
    for (long i = tid; i < total4; i += 256) {
        float4 v = b4[i];
        acc = fmaf(fmaxf(fmaf(v.x, A0, B0), 0.f), wa, acc);
        acc = fmaf(fmaxf(fmaf(v.y, A1, B1), 0.f), wb, acc);
        acc = fmaf(fmaxf(fmaf(v.z, A2, B2), 0.f), wc, acc);
        acc = fmaf(fmaxf(fmaf(v.w, A3, B3), 0.f), wd, acc);
    }
    __shared__ float red[256];
    red[tid] = acc; __syncthreads();
    for (int off = 128; off; off >>= 1) {
        if (tid < off) red[tid] += red[tid + off];
        __syncthreads();
    }
    if (tid == 0) out[g] = (cnt > 0) ? red[0] / (float)cnt + b2[0] : 0.f;
}

// ---------------------------------------------------------------------------

extern "C" void kernel_launch(void* const* d_in, const int* in_sizes, int n_in,
                              void* d_out, int out_size, void* d_ws, size_t ws_size,
                              hipStream_t stream) {
    const float* x     = (const float*)d_in[0];
    const int*   ei    = (const int*)d_in[1];
    const int*   batch = (const int*)d_in[2];

    const int N = in_sizes[0] / 64;
    const int E = in_sizes[1] / 2;
    const int G = out_size;
    const int Etot = E + N;
    const int NB = (N + BSIZE - 1) >> BSHIFT;

    const int* srcA = ei;
    const int* dstA = ei + E;

    const float* Wl[3]; const float* bl[3]; const float* Wr[3];
    const float* br[3]; const float* att[3]; const float* bb[3];
    for (int l = 0; l < 3; ++l) {
        int base = 3 + 6 * l;
        Wl[l]  = (const float*)d_in[base + 0];
        bl[l]  = (const float*)d_in[base + 1];
        Wr[l]  = (const float*)d_in[base + 2];
        br[l]  = (const float*)d_in[base + 3];
        att[l] = (const float*)d_in[base + 4];
        bb[l]  = (const float*)d_in[base + 5];
    }
    const float* mW0 = (const float*)d_in[21];
    const float* mb0 = (const float*)d_in[22];
    const float* g0  = (const float*)d_in[23];
    const float* be0 = (const float*)d_in[24];
    const float* mW1 = (const float*)d_in[25];
    const float* mb1 = (const float*)d_in[26];
    const float* g1  = (const float*)d_in[27];
    const float* be1 = (const float*)d_in[28];
    const float* mW2 = (const float*)d_in[29];
    const float* mb2 = (const float*)d_in[30];

    // ---- workspace carve ----
    char* w = (char*)d_ws;
    auto alloc = [&](size_t bytes) -> void* {
        void* p = (void*)w;
        w += (bytes + 255) & ~(size_t)255;
        return p;
    };
    int*    rowptr = (int*)alloc((size_t)(N + 1) * 4);
    int*    csr    = (int*)alloc((size_t)Etot * 4);
    int*    bcnt   = (int*)alloc(512 * 4);
    int*    bbase  = (int*)alloc(520 * 4);
    int*    bcur   = (int*)alloc(512 * 4);
    // xl(half,12.8MB) + xr(f32,25.6MB) + zext(12.8MB) contiguous; z spans them
    __half* xl     = (__half*)alloc((size_t)N * 64 * 2);
    float*  xr     = (float*)alloc((size_t)N * 64 * 4);
    float*  zext   = (float*)alloc((size_t)N * 32 * 4);
    float*  h      = (float*)alloc((size_t)N * 64 * 4);
    float*  stats  = (float*)alloc(8 * 128 * 4);
    float*  z      = (float*)xl;          // [N,128] fp32 spans xl+xr+zext
    unsigned* ebuf = (unsigned*)h;        // dead before h is live
    (void)zext;

    float* sum0 = stats;        float* sq0 = stats + 128;
    float* mu0  = stats + 256;  float* iv0 = stats + 384;
    float* sum1 = stats + 512;  float* sq1 = stats + 640;
    float* mu1  = stats + 768;  float* iv1 = stats + 896;

    // ---- bucketed CSR build ----
    hipMemsetAsync(bcnt, 0, 512 * 4, stream);
    k_bcount<<<256, 256, 0, stream>>>(dstA, bcnt, E, N);
    k_bscan<<<1, 512, 0, stream>>>(bcnt, bbase, bcur, rowptr, NB, N, Etot);
    k_bpart<<<256, 256, 0, stream>>>(srcA, dstA, bcur, ebuf, E, N);
    k_bfill<<<NB, 512, 0, stream>>>(ebuf, bbase, rowptr, csr, N, NB);

    // ---- 3x GATv2 ----
    int nodeBlocks = (N + 3) / 4;
    const float* hin = x;
    for (int l = 0; l < 3; ++l) {
        k_gat_gemm<<<2048, 256, 0, stream>>>(hin, Wl[l], bl[l], Wr[l], br[l],
                                             xl, xr, N);
        k_gat_edge<<<nodeBlocks, 256, 0, stream>>>(xl, xr, rowptr, csr,
                                                   att[l], bb[l], h, N,
                                                   (l < 2) ? 1 : 0);
        hin = h;
    }

    // ---- MLP layer 0: 64 -> 128 (stats for BN0) ----
    hipMemsetAsync(sum0, 0, 2 * 128 * 4, stream);
    k_mlp_gemm<64, 128, 0><<<2048, 256, 0, stream>>>(
        h, mW0, mb0, z, sum0, sq0, nullptr, nullptr, nullptr, nullptr, N);
    k_bn_fin<<<1, 128, 0, stream>>>(sum0, sq0, mu0, iv0, N, 128);

    // ---- MLP layer 1: 128 -> 64, BN0+ReLU fused into staging ----
    hipMemsetAsync(sum1, 0, 2 * 128 * 4, stream);
    k_mlp_gemm<128, 64, 1><<<2048, 256, 0, stream>>>(
        z, mW1, mb1, h, sum1, sq1, mu0, iv0, g0, be0, N);
    k_bn_fin<<<1, 64, 0, stream>>>(sum1, sq1, mu1, iv1, N, 64);

    // ---- fused BN1+ReLU + final linear + segmented mean pool ----
    k_pool_seg<<<G, 256, 0, stream>>>(h, mW2, mb2, batch, mu1, iv1, g1, be1,
                                      (float*)d_out, N);
}